// Round 9
// baseline (745.812 us; speedup 1.0000x reference)
//
#include <hip/hip_runtime.h>
#include <hip/hip_bf16.h>

#define NN 50000
#define NE 600000
#define DIM 128
#define VOCAB 30000
#define NEG 0.2f
#define GEPS 1e-16f

typedef __attribute__((ext_vector_type(8))) short bf16x8;
typedef __attribute__((ext_vector_type(4))) float f32x4;

__device__ __forceinline__ float leaky(float x) { return x > 0.f ? x : NEG * x; }

// bf16 split helpers (RNE)
__device__ __forceinline__ ushort f2bf(float f) {
  uint x = __float_as_uint(f);
  x += 0x7FFFu + ((x >> 16) & 1u);
  return (ushort)(x >> 16);
}
__device__ __forceinline__ float bf2f(ushort u) { return __uint_as_float(((uint)u) << 16); }

// ---------------- one-time: split embed into bf16 hi/lo ----------------
__global__ __launch_bounds__(256) void k_split(const float* __restrict__ src,
                                               ushort* __restrict__ hi,
                                               ushort* __restrict__ lo, int n4) {
  int i = blockIdx.x * 256 + threadIdx.x;
  if (i >= n4) return;
  float4 v = ((const float4*)src)[i];
  ushort4 h, l;
  h.x = f2bf(v.x); l.x = f2bf(v.x - bf2f(h.x));
  h.y = f2bf(v.y); l.y = f2bf(v.y - bf2f(h.y));
  h.z = f2bf(v.z); l.z = f2bf(v.z - bf2f(h.z));
  h.w = f2bf(v.w); l.w = f2bf(v.w - bf2f(h.w));
  ((ushort4*)hi)[i] = h;
  ((ushort4*)lo)[i] = l;
}

// ---------------- one-time: split W + pack into MFMA B-fragment order ------
__global__ __launch_bounds__(256) void k_packw(const float* __restrict__ W,
                                               ushort* __restrict__ wph,
                                               ushort* __restrict__ wpl) {
  int i = blockIdx.x * 256 + threadIdx.x;
  if (i >= 3 * 128 * 128) return;
  int ll = i >> 14, rem = i & 16383, k = rem >> 7, n = rem & 127;
  float v = W[i];
  ushort h = f2bf(v), l = f2bf(v - bf2f(h));
  int ct = n >> 4, ln = n & 15, kc = k >> 5, kr = k & 31;
  int lane = (kr >> 3) * 16 + ln, j = kr & 7;
  size_t dst = ((((size_t)ll * 8 + ct) * 4 + kc) * 64 + lane) * 8 + j;
  wph[dst] = h;
  wpl[dst] = l;
}

// ---------------- CSR build ----------------
__global__ __launch_bounds__(256) void k_count(const int* __restrict__ d1,
                                               const int* __restrict__ d2,
                                               int* __restrict__ cnt, int netot) {
  int e = blockIdx.x * blockDim.x + threadIdx.x;
  if (e >= netot) return;
  int dst = (e < NE) ? d1[e] : d2[e - NE] + NN;
  atomicAdd(&cnt[dst], 1);
}

__global__ __launch_bounds__(1024) void k_scan1(const int* __restrict__ cnt,
                                                int* __restrict__ roff,
                                                int* __restrict__ partials, int nn) {
  __shared__ int part[1024];
  const int t = threadIdx.x;
  const int idx = blockIdx.x * 1024 + t;
  int v = (idx < nn) ? cnt[idx] : 0;
  part[t] = v;
  __syncthreads();
  for (int off = 1; off < 1024; off <<= 1) {
    int x = (t >= off) ? part[t - off] : 0;
    __syncthreads();
    part[t] += x;
    __syncthreads();
  }
  if (idx < nn) roff[idx] = part[t] - v;
  if (t == 1023) partials[blockIdx.x] = part[1023];
}

__global__ __launch_bounds__(128) void k_scan2(int* __restrict__ partials, int nb) {
  __shared__ int part[128];
  const int t = threadIdx.x;
  int v = (t < nb) ? partials[t] : 0;
  part[t] = v;
  __syncthreads();
  for (int off = 1; off < 128; off <<= 1) {
    int x = (t >= off) ? part[t - off] : 0;
    __syncthreads();
    part[t] += x;
    __syncthreads();
  }
  if (t < nb) partials[t] = part[t] - v;
}

__global__ __launch_bounds__(1024) void k_scan3(int* __restrict__ roff,
                                                int* __restrict__ cur,
                                                const int* __restrict__ partials,
                                                int nn, int netot) {
  int idx = blockIdx.x * 1024 + threadIdx.x;
  if (idx < nn) {
    int v = roff[idx] + partials[blockIdx.x];
    roff[idx] = v;
    cur[idx] = v;
  }
  if (idx == 0) roff[nn] = netot;
}

__global__ __launch_bounds__(256) void k_fill(const int* __restrict__ s1,
                                              const int* __restrict__ d1,
                                              const int* __restrict__ s2,
                                              const int* __restrict__ d2,
                                              int* __restrict__ cur,
                                              int* __restrict__ ssrc, int netot) {
  int e = blockIdx.x * blockDim.x + threadIdx.x;
  if (e >= netot) return;
  int s, d;
  if (e < NE) { s = s1[e]; d = d1[e]; }
  else        { s = s2[e - NE] + NN; d = d2[e - NE] + NN; }
  int p = atomicAdd(&cur[d], 1);
  ssrc[p] = s;
}

// ---------------- linear via split-bf16 MFMA ----------------
__global__ __launch_bounds__(256) void k_linear(const ushort* __restrict__ Ahi,
                                                const ushort* __restrict__ Alo,
                                                const int* __restrict__ iA,
                                                const int* __restrict__ iB,
                                                const ushort* __restrict__ wph,
                                                const ushort* __restrict__ wpl,
                                                const float* __restrict__ a_src,
                                                const float* __restrict__ a_dst,
                                                float* __restrict__ hlin,
                                                float* __restrict__ asrc,
                                                float* __restrict__ adst, int ntot) {
  const int lane = threadIdx.x & 63;
  const int wv = threadIdx.x >> 6;
  const int m0 = blockIdx.x * 64 + wv * 16;
  const int ln = lane & 15, lh = lane >> 4;

  int m = m0 + ln;
  int mc = min(m, ntot - 1);
  int gr = mc;
  if (iA) gr = (mc < NN) ? iA[mc] : iB[mc - NN];
  const size_t abase = (size_t)gr * 128 + lh * 8;

  bf16x8 ah[4], al[4];
#pragma unroll
  for (int kc = 0; kc < 4; kc++) {
    ah[kc] = *(const bf16x8*)(Ahi + abase + kc * 32);
    al[kc] = *(const bf16x8*)(Alo + abase + kc * 32);
  }

  f32x4 acc[8];
#pragma unroll
  for (int ct = 0; ct < 8; ct++) acc[ct] = (f32x4){0.f, 0.f, 0.f, 0.f};

#pragma unroll
  for (int ct = 0; ct < 8; ct++) {
    const ushort* bh = wph + (size_t)ct * 2048 + lane * 8;
    const ushort* bl = wpl + (size_t)ct * 2048 + lane * 8;
#pragma unroll
    for (int kc = 0; kc < 4; kc++) {
      bf16x8 vh = *(const bf16x8*)(bh + kc * 512);
      bf16x8 vl = *(const bf16x8*)(bl + kc * 512);
      acc[ct] = __builtin_amdgcn_mfma_f32_16x16x32_bf16(ah[kc], vh, acc[ct], 0, 0, 0);
      acc[ct] = __builtin_amdgcn_mfma_f32_16x16x32_bf16(al[kc], vh, acc[ct], 0, 0, 0);
      acc[ct] = __builtin_amdgcn_mfma_f32_16x16x32_bf16(ah[kc], vl, acc[ct], 0, 0, 0);
    }
  }

  const int rbase = m0 + lh * 4;
#pragma unroll
  for (int r = 0; r < 4; r++) {
    int row = rbase + r;
    if (row < ntot) {
      float* dst = hlin + (size_t)row * 128 + ln;
#pragma unroll
      for (int ct = 0; ct < 8; ct++) dst[ct * 16] = acc[ct][r];
    }
  }

  float av[8], dv[8];
#pragma unroll
  for (int ct = 0; ct < 8; ct++) {
    av[ct] = a_src[ct * 16 + ln];
    dv[ct] = a_dst[ct * 16 + ln];
  }
#pragma unroll
  for (int r = 0; r < 4; r++) {
    float s0 = 0.f, s1 = 0.f, s2 = 0.f, s3 = 0.f;
    float d0 = 0.f, d1 = 0.f, d2 = 0.f, d3 = 0.f;
#pragma unroll
    for (int ct = 0; ct < 8; ct++) {
      float x = acc[ct][r];
      if ((ct >> 1) == 0) { s0 += x * av[ct]; d0 += x * dv[ct]; }
      else if ((ct >> 1) == 1) { s1 += x * av[ct]; d1 += x * dv[ct]; }
      else if ((ct >> 1) == 2) { s2 += x * av[ct]; d2 += x * dv[ct]; }
      else { s3 += x * av[ct]; d3 += x * dv[ct]; }
    }
#pragma unroll
    for (int off = 1; off < 16; off <<= 1) {
      s0 += __shfl_xor(s0, off); s1 += __shfl_xor(s1, off);
      s2 += __shfl_xor(s2, off); s3 += __shfl_xor(s3, off);
      d0 += __shfl_xor(d0, off); d1 += __shfl_xor(d1, off);
      d2 += __shfl_xor(d2, off); d3 += __shfl_xor(d3, off);
    }
    int row = rbase + r;
    if (ln == 0 && row < ntot) {
      ((float4*)asrc)[row] = make_float4(s0, s1, s2, s3);
      ((float4*)adst)[row] = make_float4(d0, d1, d2, d3);
    }
  }
}

// ---------------- aggregate v4: one wave per TWO dst nodes -----------------
// Doubles in-flight row gathers (32/wave) to hide the staging->gather latency
// chain. All deg-dependent branches are wave-uniform. Outputs bf16 hi/lo.
__global__ __launch_bounds__(256) void k_aggregate(const float* __restrict__ hlin,
                                                   const float* __restrict__ asrcv,
                                                   const float* __restrict__ adstv,
                                                   const int* __restrict__ roff,
                                                   const int* __restrict__ ssrc,
                                                   const float* __restrict__ bias,
                                                   ushort* __restrict__ h_hi,
                                                   ushort* __restrict__ h_lo, int ntot) {
  const int lane = threadIdx.x & 63;
  const int w = blockIdx.x * 4 + (threadIdx.x >> 6);
  const int nA = 2 * w;
  if (nA >= ntot) return;
  const int nB = nA + 1;
  const bool hasB = nB < ntot;
  const int p = lane >> 5;
  const int c = lane & 31;
  const int hc = c >> 3;
  const int sub = lane & 15;
  const int hs = lane >> 4;

  const int begA = roff[nA], degA = roff[nA + 1] - begA;
  const int begB = hasB ? roff[nB] : 0;
  const int degB = hasB ? roff[nB + 1] - begB : 0;

  const float adhA = adstv[nA * 4 + hs];
  const float adhB = hasB ? adstv[nB * 4 + hs] : 0.f;
  const float pselfA = __expf(leaky(asrcv[nA * 4 + hc] + adstv[nA * 4 + hc]));
  const float pselfB = hasB ? __expf(leaky(asrcv[nB * 4 + hc] + adstv[nB * 4 + hc])) : 0.f;

  float4 hvA = ((const float4*)hlin)[(size_t)nA * 32 + c];
  float4 hvB = hasB ? ((const float4*)hlin)[(size_t)nB * 32 + c]
                    : make_float4(0.f, 0.f, 0.f, 0.f);

  float4 accA, accB;
  float dhA, dhB;
  if (p == 0) {
    accA = make_float4(pselfA * hvA.x, pselfA * hvA.y, pselfA * hvA.z, pselfA * hvA.w);
    dhA = pselfA;
    accB = make_float4(pselfB * hvB.x, pselfB * hvB.y, pselfB * hvB.z, pselfB * hvB.w);
    dhB = pselfB;
  } else {
    accA = make_float4(0.f, 0.f, 0.f, 0.f); dhA = 0.f;
    accB = make_float4(0.f, 0.f, 0.f, 0.f); dhB = 0.f;
  }

  const int maxd = max(degA, degB);
  for (int base = 0; base < maxd; base += 16) {
    const bool doA = base < degA;
    const bool doB = base < degB;
    int sA = nA; float pxA = 0.f;
    if (doA) {
      int cnt = min(degA - base, 16);
      if (sub < cnt) {
        sA = ssrc[begA + base + sub];
        pxA = __expf(leaky(asrcv[sA * 4 + hs] + adhA));
      }
    }
    int sB = nB; float pxB = 0.f;
    if (doB) {
      int cnt = min(degB - base, 16);
      if (sub < cnt) {
        sB = ssrc[begB + base + sub];
        pxB = __expf(leaky(asrcv[sB * 4 + hs] + adhB));
      }
    }
    float exA[8]; float4 ldA[8];
    if (doA) {
#pragma unroll
      for (int jj = 0; jj < 8; jj++) {
        int e = 2 * jj + p;
        int sj = __shfl(sA, e);
        exA[jj] = __shfl(pxA, hc * 16 + e);
        ldA[jj] = ((const float4*)hlin)[(size_t)sj * 32 + c];
      }
    }
    float exB[8]; float4 ldB[8];
    if (doB) {
#pragma unroll
      for (int jj = 0; jj < 8; jj++) {
        int e = 2 * jj + p;
        int sj = __shfl(sB, e);
        exB[jj] = __shfl(pxB, hc * 16 + e);
        ldB[jj] = ((const float4*)hlin)[(size_t)sj * 32 + c];
      }
    }
    if (doA) {
#pragma unroll
      for (int jj = 0; jj < 8; jj++) {
        accA.x += exA[jj] * ldA[jj].x;
        accA.y += exA[jj] * ldA[jj].y;
        accA.z += exA[jj] * ldA[jj].z;
        accA.w += exA[jj] * ldA[jj].w;
        dhA += exA[jj];
      }
    }
    if (doB) {
#pragma unroll
      for (int jj = 0; jj < 8; jj++) {
        accB.x += exB[jj] * ldB[jj].x;
        accB.y += exB[jj] * ldB[jj].y;
        accB.z += exB[jj] * ldB[jj].z;
        accB.w += exB[jj] * ldB[jj].w;
        dhB += exB[jj];
      }
    }
  }

  accA.x += __shfl_xor(accA.x, 32);
  accA.y += __shfl_xor(accA.y, 32);
  accA.z += __shfl_xor(accA.z, 32);
  accA.w += __shfl_xor(accA.w, 32);
  dhA += __shfl_xor(dhA, 32);
  accB.x += __shfl_xor(accB.x, 32);
  accB.y += __shfl_xor(accB.y, 32);
  accB.z += __shfl_xor(accB.z, 32);
  accB.w += __shfl_xor(accB.w, 32);
  dhB += __shfl_xor(dhB, 32);

  float4 bv = ((const float4*)bias)[c];
  if (p == 0) {
    {
      float inv = 1.f / (dhA + GEPS);
      float4 o;
      o.x = fmaxf(accA.x * inv + bv.x, 0.f);
      o.y = fmaxf(accA.y * inv + bv.y, 0.f);
      o.z = fmaxf(accA.z * inv + bv.z, 0.f);
      o.w = fmaxf(accA.w * inv + bv.w, 0.f);
      ushort4 uh, ul;
      uh.x = f2bf(o.x); ul.x = f2bf(o.x - bf2f(uh.x));
      uh.y = f2bf(o.y); ul.y = f2bf(o.y - bf2f(uh.y));
      uh.z = f2bf(o.z); ul.z = f2bf(o.z - bf2f(uh.z));
      uh.w = f2bf(o.w); ul.w = f2bf(o.w - bf2f(uh.w));
      ((ushort4*)h_hi)[(size_t)nA * 32 + c] = uh;
      ((ushort4*)h_lo)[(size_t)nA * 32 + c] = ul;
    }
    if (hasB) {
      float inv = 1.f / (dhB + GEPS);
      float4 o;
      o.x = fmaxf(accB.x * inv + bv.x, 0.f);
      o.y = fmaxf(accB.y * inv + bv.y, 0.f);
      o.z = fmaxf(accB.z * inv + bv.z, 0.f);
      o.w = fmaxf(accB.w * inv + bv.w, 0.f);
      ushort4 uh, ul;
      uh.x = f2bf(o.x); ul.x = f2bf(o.x - bf2f(uh.x));
      uh.y = f2bf(o.y); ul.y = f2bf(o.y - bf2f(uh.y));
      uh.z = f2bf(o.z); ul.z = f2bf(o.z - bf2f(uh.z));
      uh.w = f2bf(o.w); ul.w = f2bf(o.w - bf2f(uh.w));
      ((ushort4*)h_hi)[(size_t)nB * 32 + c] = uh;
      ((ushort4*)h_lo)[(size_t)nB * 32 + c] = ul;
    }
  }
}

// ---------------- global attention pooling (reads bf16 hi/lo) ----------------
__global__ __launch_bounds__(256) void k_pool(const ushort* __restrict__ hh,
                                              const ushort* __restrict__ hl,
                                              const float* __restrict__ gate_w,
                                              const float* __restrict__ gate_b,
                                              float* __restrict__ acc_out) {
  const int lane = threadIdx.x & 63;
  const int widg = blockIdx.x * 4 + (threadIdx.x >> 6);
  const int nw = gridDim.x * 4;
  const float w0 = gate_w[lane * 2], w1 = gate_w[lane * 2 + 1];
  const float gb = gate_b[0];
  float acc0 = 0.f, acc1 = 0.f, se = 0.f;
  for (int n = widg; n < NN; n += nw) {
    ushort2 h2 = ((const ushort2*)hh)[(size_t)n * 64 + lane];
    ushort2 l2 = ((const ushort2*)hl)[(size_t)n * 64 + lane];
    float hx = bf2f(h2.x) + bf2f(l2.x);
    float hy = bf2f(h2.y) + bf2f(l2.y);
    float p = hx * w0 + hy * w1;
#pragma unroll
    for (int off = 1; off < 64; off <<= 1) p += __shfl_xor(p, off);
    float sg = 1.f / (1.f + __expf(-(p + gb)));
    float e = __expf(sg);
    se += e;
    acc0 += e * hx;
    acc1 += e * hy;
  }
  atomicAdd(&acc_out[lane * 2], acc0);
  atomicAdd(&acc_out[lane * 2 + 1], acc1);
  if (lane == 0) atomicAdd(&acc_out[128], se);
}

// ---------------- final MLP ----------------
__global__ __launch_bounds__(128) void k_mlp(const float* __restrict__ p1,
                                             const float* __restrict__ p2,
                                             const float* __restrict__ fc1_w,
                                             const float* __restrict__ fc1_b,
                                             const float* __restrict__ fc2_w,
                                             const float* __restrict__ fc2_b,
                                             float* __restrict__ out) {
  __shared__ float cat[256];
  __shared__ float red[2];
  const int t = threadIdx.x;
  cat[t] = p1[t] / p1[128];
  cat[128 + t] = p2[t] / p2[128];
  __syncthreads();
  float a = fc1_b[t];
  for (int k = 0; k < 256; k++) a += cat[k] * fc1_w[k * 128 + t];
  a = fmaxf(a, 0.f);
  float v = a * fc2_w[t];
#pragma unroll
  for (int off = 1; off < 64; off <<= 1) v += __shfl_xor(v, off);
  if ((t & 63) == 0) red[t >> 6] = v;
  __syncthreads();
  if (t == 0) out[0] = red[0] + red[1] + fc2_b[0];
}

extern "C" void kernel_launch(void* const* d_in, const int* in_sizes, int n_in,
                              void* d_out, int out_size, void* d_ws, size_t ws_size,
                              hipStream_t stream) {
  (void)in_sizes; (void)n_in; (void)out_size;
  const int* x1 = (const int*)d_in[0];
  const int* x2 = (const int*)d_in[1];
  const int* ei1 = (const int*)d_in[2];
  const int* ei2 = (const int*)d_in[3];
  const float* embed = (const float*)d_in[4];
  const float* W = (const float*)d_in[5];
  const float* attS = (const float*)d_in[6];
  const float* attD = (const float*)d_in[7];
  const float* bias = (const float*)d_in[8];
  const float* gw = (const float*)d_in[9];
  const float* gb = (const float*)d_in[10];
  const float* f1w = (const float*)d_in[11];
  const float* f1b = (const float*)d_in[12];
  const float* f2w = (const float*)d_in[13];
  const float* f2b = (const float*)d_in[14];
  float* out = (float*)d_out;

  auto req = [](int nt, int net) {
    size_t s = 0;
    auto pad = [&](size_t b) { s = (s + b + 255) & ~size_t(255); };
    pad(size_t(nt) * DIM * 2);        // h_hi
    pad(size_t(nt) * DIM * 2);        // h_lo
    pad(size_t(nt) * DIM * 4);        // h_lin
    pad(size_t(VOCAB) * DIM * 2);     // e_hi
    pad(size_t(VOCAB) * DIM * 2);     // e_lo
    pad(3 * 16384 * 2);               // wp_hi
    pad(3 * 16384 * 2);               // wp_lo
    pad(size_t(nt) * 16);             // asrc
    pad(size_t(nt) * 16);             // adst
    pad(size_t(nt + 1) * 4);          // roff
    pad(size_t(nt) * 4);              // cur
    pad(size_t(net) * 4);             // ssrc
    pad(128 * 4);                     // partials
    pad(2 * 129 * 4);                 // pool
    return s;
  };
  const bool combined = ws_size >= req(2 * NN, 2 * NE);
  const int nt = combined ? 2 * NN : NN;
  const int net = combined ? 2 * NE : NE;

  char* ws = (char*)d_ws;
  size_t off = 0;
  auto alloc = [&](size_t bytes) {
    void* p = ws + off;
    off = (off + bytes + 255) & ~size_t(255);
    return p;
  };
  ushort* h_hi = (ushort*)alloc(size_t(nt) * DIM * 2);
  ushort* h_lo = (ushort*)alloc(size_t(nt) * DIM * 2);
  float* h_lin = (float*)alloc(size_t(nt) * DIM * 4);
  ushort* e_hi = (ushort*)alloc(size_t(VOCAB) * DIM * 2);
  ushort* e_lo = (ushort*)alloc(size_t(VOCAB) * DIM * 2);
  ushort* wp_hi = (ushort*)alloc(3 * 16384 * 2);
  ushort* wp_lo = (ushort*)alloc(3 * 16384 * 2);
  float* asrc = (float*)alloc(size_t(nt) * 16);
  float* adst = (float*)alloc(size_t(nt) * 16);
  int* roff = (int*)alloc(size_t(nt + 1) * 4);
  int* cur = (int*)alloc(size_t(nt) * 4);
  int* ssrc = (int*)alloc(size_t(net) * 4);
  int* partials = (int*)alloc(128 * 4);
  float* pool = (float*)alloc(2 * 129 * 4);

  hipMemsetAsync(pool, 0, 2 * 129 * 4, stream);

  const int esplit4 = VOCAB * DIM / 4;
  k_split<<<(esplit4 + 255) / 256, 256, 0, stream>>>(embed, e_hi, e_lo, esplit4);
  k_packw<<<(3 * 128 * 128 + 255) / 256, 256, 0, stream>>>(W, wp_hi, wp_lo);

  const int nb = (nt + 1023) / 1024;
  const int lgrid = (nt + 63) / 64;
  const int agrid = ((nt + 1) / 2 + 3) / 4;

  auto run_graphs = [&](const int* xA, const int* xB, const int* eA, const int* eB) {
    hipMemsetAsync(cur, 0, size_t(nt) * 4, stream);
    k_count<<<(net + 255) / 256, 256, 0, stream>>>(eA + NE, eB + NE, cur, net);
    k_scan1<<<nb, 1024, 0, stream>>>(cur, roff, partials, nt);
    k_scan2<<<1, 128, 0, stream>>>(partials, nb);
    k_scan3<<<nb, 1024, 0, stream>>>(roff, cur, partials, nt, net);
    k_fill<<<(net + 255) / 256, 256, 0, stream>>>(eA, eA + NE, eB, eB + NE, cur, ssrc, net);
    for (int l = 0; l < 3; ++l) {
      if (l == 0) {
        k_linear<<<lgrid, 256, 0, stream>>>(
            e_hi, e_lo, xA, xB, wp_hi, wp_lo, attS, attD, h_lin, asrc, adst, nt);
      } else {
        k_linear<<<lgrid, 256, 0, stream>>>(
            h_hi, h_lo, nullptr, nullptr, wp_hi + l * 16384, wp_lo + l * 16384,
            attS + l * DIM, attD + l * DIM, h_lin, asrc, adst, nt);
      }
      k_aggregate<<<agrid, 256, 0, stream>>>(
          h_lin, asrc, adst, roff, ssrc, bias + l * DIM, h_hi, h_lo, nt);
    }
  };

  if (combined) {
    run_graphs(x1, x2, ei1, ei2);
    k_pool<<<128, 256, 0, stream>>>(h_hi, h_lo, gw, gb, pool);
    k_pool<<<128, 256, 0, stream>>>(h_hi + size_t(NN) * DIM, h_lo + size_t(NN) * DIM,
                                    gw, gb, pool + 129);
  } else {
    run_graphs(x1, x1, ei1, ei1);
    k_pool<<<128, 256, 0, stream>>>(h_hi, h_lo, gw, gb, pool);
    run_graphs(x2, x2, ei2, ei2);
    k_pool<<<128, 256, 0, stream>>>(h_hi, h_lo, gw, gb, pool + 129);
  }
  k_mlp<<<1, 128, 0, stream>>>(pool, pool + 129, f1w, f1b, f2w, f2b, out);
}

// Round 10
// 723.189 us; speedup vs baseline: 1.0313x; 1.0313x over previous
//
#include <hip/hip_runtime.h>
#include <hip/hip_bf16.h>

#define NN 50000
#define NE 600000
#define DIM 128
#define VOCAB 30000
#define NEG 0.2f
#define GEPS 1e-16f

typedef __attribute__((ext_vector_type(8))) short bf16x8;
typedef __attribute__((ext_vector_type(4))) float f32x4;

__device__ __forceinline__ float leaky(float x) { return x > 0.f ? x : NEG * x; }

// bf16 split helpers (RNE)
__device__ __forceinline__ ushort f2bf(float f) {
  uint x = __float_as_uint(f);
  x += 0x7FFFu + ((x >> 16) & 1u);
  return (ushort)(x >> 16);
}
__device__ __forceinline__ float bf2f(ushort u) { return __uint_as_float(((uint)u) << 16); }

// ---------------- one-time: split embed into bf16 hi/lo ----------------
__global__ __launch_bounds__(256) void k_split(const float* __restrict__ src,
                                               ushort* __restrict__ hi,
                                               ushort* __restrict__ lo, int n4) {
  int i = blockIdx.x * 256 + threadIdx.x;
  if (i >= n4) return;
  float4 v = ((const float4*)src)[i];
  ushort4 h, l;
  h.x = f2bf(v.x); l.x = f2bf(v.x - bf2f(h.x));
  h.y = f2bf(v.y); l.y = f2bf(v.y - bf2f(h.y));
  h.z = f2bf(v.z); l.z = f2bf(v.z - bf2f(h.z));
  h.w = f2bf(v.w); l.w = f2bf(v.w - bf2f(h.w));
  ((ushort4*)hi)[i] = h;
  ((ushort4*)lo)[i] = l;
}

// ---------------- one-time: split W + pack into MFMA B-fragment order ------
__global__ __launch_bounds__(256) void k_packw(const float* __restrict__ W,
                                               ushort* __restrict__ wph,
                                               ushort* __restrict__ wpl) {
  int i = blockIdx.x * 256 + threadIdx.x;
  if (i >= 3 * 128 * 128) return;
  int ll = i >> 14, rem = i & 16383, k = rem >> 7, n = rem & 127;
  float v = W[i];
  ushort h = f2bf(v), l = f2bf(v - bf2f(h));
  int ct = n >> 4, ln = n & 15, kc = k >> 5, kr = k & 31;
  int lane = (kr >> 3) * 16 + ln, j = kr & 7;
  size_t dst = ((((size_t)ll * 8 + ct) * 4 + kc) * 64 + lane) * 8 + j;
  wph[dst] = h;
  wpl[dst] = l;
}

// ---------------- CSR build ----------------
__global__ __launch_bounds__(256) void k_count(const int* __restrict__ d1,
                                               const int* __restrict__ d2,
                                               int* __restrict__ cnt, int netot) {
  int e = blockIdx.x * blockDim.x + threadIdx.x;
  if (e >= netot) return;
  int dst = (e < NE) ? d1[e] : d2[e - NE] + NN;
  atomicAdd(&cnt[dst], 1);
}

__global__ __launch_bounds__(1024) void k_scan1(const int* __restrict__ cnt,
                                                int* __restrict__ roff,
                                                int* __restrict__ partials, int nn) {
  __shared__ int part[1024];
  const int t = threadIdx.x;
  const int idx = blockIdx.x * 1024 + t;
  int v = (idx < nn) ? cnt[idx] : 0;
  part[t] = v;
  __syncthreads();
  for (int off = 1; off < 1024; off <<= 1) {
    int x = (t >= off) ? part[t - off] : 0;
    __syncthreads();
    part[t] += x;
    __syncthreads();
  }
  if (idx < nn) roff[idx] = part[t] - v;
  if (t == 1023) partials[blockIdx.x] = part[1023];
}

__global__ __launch_bounds__(128) void k_scan2(int* __restrict__ partials, int nb) {
  __shared__ int part[128];
  const int t = threadIdx.x;
  int v = (t < nb) ? partials[t] : 0;
  part[t] = v;
  __syncthreads();
  for (int off = 1; off < 128; off <<= 1) {
    int x = (t >= off) ? part[t - off] : 0;
    __syncthreads();
    part[t] += x;
    __syncthreads();
  }
  if (t < nb) partials[t] = part[t] - v;
}

__global__ __launch_bounds__(1024) void k_scan3(int* __restrict__ roff,
                                                int* __restrict__ cur,
                                                const int* __restrict__ partials,
                                                int nn, int netot) {
  int idx = blockIdx.x * 1024 + threadIdx.x;
  if (idx < nn) {
    int v = roff[idx] + partials[blockIdx.x];
    roff[idx] = v;
    cur[idx] = v;
  }
  if (idx == 0) roff[nn] = netot;
}

__global__ __launch_bounds__(256) void k_fill(const int* __restrict__ s1,
                                              const int* __restrict__ d1,
                                              const int* __restrict__ s2,
                                              const int* __restrict__ d2,
                                              int* __restrict__ cur,
                                              int* __restrict__ ssrc, int netot) {
  int e = blockIdx.x * blockDim.x + threadIdx.x;
  if (e >= netot) return;
  int s, d;
  if (e < NE) { s = s1[e]; d = d1[e]; }
  else        { s = s2[e - NE] + NN; d = d2[e - NE] + NN; }
  int p = atomicAdd(&cur[d], 1);
  ssrc[p] = s;
}

// ---------------- linear via split-bf16 MFMA ----------------
__global__ __launch_bounds__(256) void k_linear(const ushort* __restrict__ Ahi,
                                                const ushort* __restrict__ Alo,
                                                const int* __restrict__ iA,
                                                const int* __restrict__ iB,
                                                const ushort* __restrict__ wph,
                                                const ushort* __restrict__ wpl,
                                                const float* __restrict__ a_src,
                                                const float* __restrict__ a_dst,
                                                float* __restrict__ hlin,
                                                float* __restrict__ asrc,
                                                float* __restrict__ adst, int ntot) {
  const int lane = threadIdx.x & 63;
  const int wv = threadIdx.x >> 6;
  const int m0 = blockIdx.x * 64 + wv * 16;
  const int ln = lane & 15, lh = lane >> 4;

  int m = m0 + ln;
  int mc = min(m, ntot - 1);
  int gr = mc;
  if (iA) gr = (mc < NN) ? iA[mc] : iB[mc - NN];
  const size_t abase = (size_t)gr * 128 + lh * 8;

  bf16x8 ah[4], al[4];
#pragma unroll
  for (int kc = 0; kc < 4; kc++) {
    ah[kc] = *(const bf16x8*)(Ahi + abase + kc * 32);
    al[kc] = *(const bf16x8*)(Alo + abase + kc * 32);
  }

  f32x4 acc[8];
#pragma unroll
  for (int ct = 0; ct < 8; ct++) acc[ct] = (f32x4){0.f, 0.f, 0.f, 0.f};

#pragma unroll
  for (int ct = 0; ct < 8; ct++) {
    const ushort* bh = wph + (size_t)ct * 2048 + lane * 8;
    const ushort* bl = wpl + (size_t)ct * 2048 + lane * 8;
#pragma unroll
    for (int kc = 0; kc < 4; kc++) {
      bf16x8 vh = *(const bf16x8*)(bh + kc * 512);
      bf16x8 vl = *(const bf16x8*)(bl + kc * 512);
      acc[ct] = __builtin_amdgcn_mfma_f32_16x16x32_bf16(ah[kc], vh, acc[ct], 0, 0, 0);
      acc[ct] = __builtin_amdgcn_mfma_f32_16x16x32_bf16(al[kc], vh, acc[ct], 0, 0, 0);
      acc[ct] = __builtin_amdgcn_mfma_f32_16x16x32_bf16(ah[kc], vl, acc[ct], 0, 0, 0);
    }
  }

  const int rbase = m0 + lh * 4;
#pragma unroll
  for (int r = 0; r < 4; r++) {
    int row = rbase + r;
    if (row < ntot) {
      float* dst = hlin + (size_t)row * 128 + ln;
#pragma unroll
      for (int ct = 0; ct < 8; ct++) dst[ct * 16] = acc[ct][r];
    }
  }

  float av[8], dv[8];
#pragma unroll
  for (int ct = 0; ct < 8; ct++) {
    av[ct] = a_src[ct * 16 + ln];
    dv[ct] = a_dst[ct * 16 + ln];
  }
#pragma unroll
  for (int r = 0; r < 4; r++) {
    float s0 = 0.f, s1 = 0.f, s2 = 0.f, s3 = 0.f;
    float d0 = 0.f, d1 = 0.f, d2 = 0.f, d3 = 0.f;
#pragma unroll
    for (int ct = 0; ct < 8; ct++) {
      float x = acc[ct][r];
      if ((ct >> 1) == 0) { s0 += x * av[ct]; d0 += x * dv[ct]; }
      else if ((ct >> 1) == 1) { s1 += x * av[ct]; d1 += x * dv[ct]; }
      else if ((ct >> 1) == 2) { s2 += x * av[ct]; d2 += x * dv[ct]; }
      else { s3 += x * av[ct]; d3 += x * dv[ct]; }
    }
#pragma unroll
    for (int off = 1; off < 16; off <<= 1) {
      s0 += __shfl_xor(s0, off); s1 += __shfl_xor(s1, off);
      s2 += __shfl_xor(s2, off); s3 += __shfl_xor(s3, off);
      d0 += __shfl_xor(d0, off); d1 += __shfl_xor(d1, off);
      d2 += __shfl_xor(d2, off); d3 += __shfl_xor(d3, off);
    }
    int row = rbase + r;
    if (ln == 0 && row < ntot) {
      ((float4*)asrc)[row] = make_float4(s0, s1, s2, s3);
      ((float4*)adst)[row] = make_float4(d0, d1, d2, d3);
    }
  }
}

// ---------------- aggregate v5: r8 pair-split consumption + staging pipeline
// One wave handles 4 consecutive nodes sequentially; stage(n+1) (roff/ssrc/
// asrcv/exp chain, ~22 VGPR) is issued before consume(n) so its latency hides
// under n's row loads. Consumption state (ld[8]) is single-instance (r9's
// doubled-state failure mode avoided).
struct Stg {
  int s; float px; float adh; float pself; float4 hv; int beg; int deg; int v;
};

__device__ __forceinline__ Stg stage_node(int n, int beg, int deg, int ntot,
                                          const float* __restrict__ hlin,
                                          const float* __restrict__ asrcv,
                                          const float* __restrict__ adstv,
                                          const int* __restrict__ ssrc,
                                          int c, int hc, int sub, int hs) {
  Stg st;
  st.beg = beg; st.deg = deg;
  st.v = n < ntot;
  int nc = st.v ? n : 0;
  st.adh = adstv[nc * 4 + hs];
  float asl = asrcv[nc * 4 + hc];
  float adl = adstv[nc * 4 + hc];
  st.pself = st.v ? __expf(leaky(asl + adl)) : 0.f;
  st.hv = ((const float4*)hlin)[(size_t)nc * 32 + c];
  st.s = nc; st.px = 0.f;
  int cnt = min(deg, 16);
  if (st.v && sub < cnt) {
    st.s = ssrc[beg + sub];
    st.px = __expf(leaky(asrcv[st.s * 4 + hs] + st.adh));
  }
  return st;
}

__device__ __forceinline__ void consume_node(const Stg& st, int n,
                                             const float* __restrict__ hlin,
                                             const float* __restrict__ asrcv,
                                             const int* __restrict__ ssrc,
                                             const float4 bv,
                                             ushort* __restrict__ h_hi,
                                             ushort* __restrict__ h_lo,
                                             int p, int c, int hc, int sub, int hs) {
  float4 acc;
  float dh;
  if (p == 0) {
    acc = make_float4(st.pself * st.hv.x, st.pself * st.hv.y,
                      st.pself * st.hv.z, st.pself * st.hv.w);
    dh = st.pself;
  } else {
    acc = make_float4(0.f, 0.f, 0.f, 0.f);
    dh = 0.f;
  }

  int s = st.s;
  float px = st.px;
  for (int b16 = 0; b16 < st.deg; b16 += 16) {
    if (b16 > 0) {  // re-stage later chunks inline (minority of nodes)
      int cnt = min(st.deg - b16, 16);
      s = n; px = 0.f;
      if (sub < cnt) {
        s = ssrc[st.beg + b16 + sub];
        px = __expf(leaky(asrcv[s * 4 + hs] + st.adh));
      }
    }
    float ex[8]; float4 ld[8];
#pragma unroll
    for (int jj = 0; jj < 8; jj++) {
      int e = 2 * jj + p;
      int sj = __shfl(s, e);
      ex[jj] = __shfl(px, hc * 16 + e);
      ld[jj] = ((const float4*)hlin)[(size_t)sj * 32 + c];
    }
#pragma unroll
    for (int jj = 0; jj < 8; jj++) {
      acc.x += ex[jj] * ld[jj].x;
      acc.y += ex[jj] * ld[jj].y;
      acc.z += ex[jj] * ld[jj].z;
      acc.w += ex[jj] * ld[jj].w;
      dh += ex[jj];
    }
  }

  acc.x += __shfl_xor(acc.x, 32);
  acc.y += __shfl_xor(acc.y, 32);
  acc.z += __shfl_xor(acc.z, 32);
  acc.w += __shfl_xor(acc.w, 32);
  dh += __shfl_xor(dh, 32);

  if (p == 0 && st.v) {
    float inv = 1.f / (dh + GEPS);
    float4 o;
    o.x = fmaxf(acc.x * inv + bv.x, 0.f);
    o.y = fmaxf(acc.y * inv + bv.y, 0.f);
    o.z = fmaxf(acc.z * inv + bv.z, 0.f);
    o.w = fmaxf(acc.w * inv + bv.w, 0.f);
    ushort4 uh, ul;
    uh.x = f2bf(o.x); ul.x = f2bf(o.x - bf2f(uh.x));
    uh.y = f2bf(o.y); ul.y = f2bf(o.y - bf2f(uh.y));
    uh.z = f2bf(o.z); ul.z = f2bf(o.z - bf2f(uh.z));
    uh.w = f2bf(o.w); ul.w = f2bf(o.w - bf2f(uh.w));
    ((ushort4*)h_hi)[(size_t)n * 32 + c] = uh;
    ((ushort4*)h_lo)[(size_t)n * 32 + c] = ul;
  }
}

__global__ __launch_bounds__(256) void k_aggregate(const float* __restrict__ hlin,
                                                   const float* __restrict__ asrcv,
                                                   const float* __restrict__ adstv,
                                                   const int* __restrict__ roff,
                                                   const int* __restrict__ ssrc,
                                                   const float* __restrict__ bias,
                                                   ushort* __restrict__ h_hi,
                                                   ushort* __restrict__ h_lo, int ntot) {
  const int lane = threadIdx.x & 63;
  const int w = blockIdx.x * 4 + (threadIdx.x >> 6);
  const int base = w * 4;
  if (base >= ntot) return;
  const int p = lane >> 5;
  const int c = lane & 31;
  const int hc = c >> 3;
  const int sub = lane & 15;
  const int hs = lane >> 4;

  int ro = 0;
  if (lane <= 4) ro = roff[min(base + lane, ntot)];
  const int b0 = __shfl(ro, 0), b1 = __shfl(ro, 1), b2 = __shfl(ro, 2);
  const int b3 = __shfl(ro, 3), b4 = __shfl(ro, 4);

  const float4 bv = ((const float4*)bias)[c];

  Stg s0 = stage_node(base + 0, b0, b1 - b0, ntot, hlin, asrcv, adstv, ssrc, c, hc, sub, hs);
  Stg s1 = stage_node(base + 1, b1, b2 - b1, ntot, hlin, asrcv, adstv, ssrc, c, hc, sub, hs);
  consume_node(s0, base + 0, hlin, asrcv, ssrc, bv, h_hi, h_lo, p, c, hc, sub, hs);
  Stg s2 = stage_node(base + 2, b2, b3 - b2, ntot, hlin, asrcv, adstv, ssrc, c, hc, sub, hs);
  consume_node(s1, base + 1, hlin, asrcv, ssrc, bv, h_hi, h_lo, p, c, hc, sub, hs);
  Stg s3 = stage_node(base + 3, b3, b4 - b3, ntot, hlin, asrcv, adstv, ssrc, c, hc, sub, hs);
  consume_node(s2, base + 2, hlin, asrcv, ssrc, bv, h_hi, h_lo, p, c, hc, sub, hs);
  consume_node(s3, base + 3, hlin, asrcv, ssrc, bv, h_hi, h_lo, p, c, hc, sub, hs);
}

// ---------------- global attention pooling (reads bf16 hi/lo) ----------------
__global__ __launch_bounds__(256) void k_pool(const ushort* __restrict__ hh,
                                              const ushort* __restrict__ hl,
                                              const float* __restrict__ gate_w,
                                              const float* __restrict__ gate_b,
                                              float* __restrict__ acc_out) {
  const int lane = threadIdx.x & 63;
  const int widg = blockIdx.x * 4 + (threadIdx.x >> 6);
  const int nw = gridDim.x * 4;
  const float w0 = gate_w[lane * 2], w1 = gate_w[lane * 2 + 1];
  const float gb = gate_b[0];
  float acc0 = 0.f, acc1 = 0.f, se = 0.f;
  for (int n = widg; n < NN; n += nw) {
    ushort2 h2 = ((const ushort2*)hh)[(size_t)n * 64 + lane];
    ushort2 l2 = ((const ushort2*)hl)[(size_t)n * 64 + lane];
    float hx = bf2f(h2.x) + bf2f(l2.x);
    float hy = bf2f(h2.y) + bf2f(l2.y);
    float p = hx * w0 + hy * w1;
#pragma unroll
    for (int off = 1; off < 64; off <<= 1) p += __shfl_xor(p, off);
    float sg = 1.f / (1.f + __expf(-(p + gb)));
    float e = __expf(sg);
    se += e;
    acc0 += e * hx;
    acc1 += e * hy;
  }
  atomicAdd(&acc_out[lane * 2], acc0);
  atomicAdd(&acc_out[lane * 2 + 1], acc1);
  if (lane == 0) atomicAdd(&acc_out[128], se);
}

// ---------------- final MLP ----------------
__global__ __launch_bounds__(128) void k_mlp(const float* __restrict__ p1,
                                             const float* __restrict__ p2,
                                             const float* __restrict__ fc1_w,
                                             const float* __restrict__ fc1_b,
                                             const float* __restrict__ fc2_w,
                                             const float* __restrict__ fc2_b,
                                             float* __restrict__ out) {
  __shared__ float cat[256];
  __shared__ float red[2];
  const int t = threadIdx.x;
  cat[t] = p1[t] / p1[128];
  cat[128 + t] = p2[t] / p2[128];
  __syncthreads();
  float a = fc1_b[t];
  for (int k = 0; k < 256; k++) a += cat[k] * fc1_w[k * 128 + t];
  a = fmaxf(a, 0.f);
  float v = a * fc2_w[t];
#pragma unroll
  for (int off = 1; off < 64; off <<= 1) v += __shfl_xor(v, off);
  if ((t & 63) == 0) red[t >> 6] = v;
  __syncthreads();
  if (t == 0) out[0] = red[0] + red[1] + fc2_b[0];
}

extern "C" void kernel_launch(void* const* d_in, const int* in_sizes, int n_in,
                              void* d_out, int out_size, void* d_ws, size_t ws_size,
                              hipStream_t stream) {
  (void)in_sizes; (void)n_in; (void)out_size;
  const int* x1 = (const int*)d_in[0];
  const int* x2 = (const int*)d_in[1];
  const int* ei1 = (const int*)d_in[2];
  const int* ei2 = (const int*)d_in[3];
  const float* embed = (const float*)d_in[4];
  const float* W = (const float*)d_in[5];
  const float* attS = (const float*)d_in[6];
  const float* attD = (const float*)d_in[7];
  const float* bias = (const float*)d_in[8];
  const float* gw = (const float*)d_in[9];
  const float* gb = (const float*)d_in[10];
  const float* f1w = (const float*)d_in[11];
  const float* f1b = (const float*)d_in[12];
  const float* f2w = (const float*)d_in[13];
  const float* f2b = (const float*)d_in[14];
  float* out = (float*)d_out;

  auto req = [](int nt, int net) {
    size_t s = 0;
    auto pad = [&](size_t b) { s = (s + b + 255) & ~size_t(255); };
    pad(size_t(nt) * DIM * 2);        // h_hi
    pad(size_t(nt) * DIM * 2);        // h_lo
    pad(size_t(nt) * DIM * 4);        // h_lin
    pad(size_t(VOCAB) * DIM * 2);     // e_hi
    pad(size_t(VOCAB) * DIM * 2);     // e_lo
    pad(3 * 16384 * 2);               // wp_hi
    pad(3 * 16384 * 2);               // wp_lo
    pad(size_t(nt) * 16);             // asrc
    pad(size_t(nt) * 16);             // adst
    pad(size_t(nt + 1) * 4);          // roff
    pad(size_t(nt) * 4);              // cur
    pad(size_t(net) * 4);             // ssrc
    pad(128 * 4);                     // partials
    pad(2 * 129 * 4);                 // pool
    return s;
  };
  const bool combined = ws_size >= req(2 * NN, 2 * NE);
  const int nt = combined ? 2 * NN : NN;
  const int net = combined ? 2 * NE : NE;

  char* ws = (char*)d_ws;
  size_t off = 0;
  auto alloc = [&](size_t bytes) {
    void* p = ws + off;
    off = (off + bytes + 255) & ~size_t(255);
    return p;
  };
  ushort* h_hi = (ushort*)alloc(size_t(nt) * DIM * 2);
  ushort* h_lo = (ushort*)alloc(size_t(nt) * DIM * 2);
  float* h_lin = (float*)alloc(size_t(nt) * DIM * 4);
  ushort* e_hi = (ushort*)alloc(size_t(VOCAB) * DIM * 2);
  ushort* e_lo = (ushort*)alloc(size_t(VOCAB) * DIM * 2);
  ushort* wp_hi = (ushort*)alloc(3 * 16384 * 2);
  ushort* wp_lo = (ushort*)alloc(3 * 16384 * 2);
  float* asrc = (float*)alloc(size_t(nt) * 16);
  float* adst = (float*)alloc(size_t(nt) * 16);
  int* roff = (int*)alloc(size_t(nt + 1) * 4);
  int* cur = (int*)alloc(size_t(nt) * 4);
  int* ssrc = (int*)alloc(size_t(net) * 4);
  int* partials = (int*)alloc(128 * 4);
  float* pool = (float*)alloc(2 * 129 * 4);

  hipMemsetAsync(pool, 0, 2 * 129 * 4, stream);

  const int esplit4 = VOCAB * DIM / 4;
  k_split<<<(esplit4 + 255) / 256, 256, 0, stream>>>(embed, e_hi, e_lo, esplit4);
  k_packw<<<(3 * 128 * 128 + 255) / 256, 256, 0, stream>>>(W, wp_hi, wp_lo);

  const int nb = (nt + 1023) / 1024;
  const int lgrid = (nt + 63) / 64;
  const int agrid = (nt + 15) / 16;  // 4 waves/block x 4 nodes/wave

  auto run_graphs = [&](const int* xA, const int* xB, const int* eA, const int* eB) {
    hipMemsetAsync(cur, 0, size_t(nt) * 4, stream);
    k_count<<<(net + 255) / 256, 256, 0, stream>>>(eA + NE, eB + NE, cur, net);
    k_scan1<<<nb, 1024, 0, stream>>>(cur, roff, partials, nt);
    k_scan2<<<1, 128, 0, stream>>>(partials, nb);
    k_scan3<<<nb, 1024, 0, stream>>>(roff, cur, partials, nt, net);
    k_fill<<<(net + 255) / 256, 256, 0, stream>>>(eA, eA + NE, eB, eB + NE, cur, ssrc, net);
    for (int l = 0; l < 3; ++l) {
      if (l == 0) {
        k_linear<<<lgrid, 256, 0, stream>>>(
            e_hi, e_lo, xA, xB, wp_hi, wp_lo, attS, attD, h_lin, asrc, adst, nt);
      } else {
        k_linear<<<lgrid, 256, 0, stream>>>(
            h_hi, h_lo, nullptr, nullptr, wp_hi + l * 16384, wp_lo + l * 16384,
            attS + l * DIM, attD + l * DIM, h_lin, asrc, adst, nt);
      }
      k_aggregate<<<agrid, 256, 0, stream>>>(
          h_lin, asrc, adst, roff, ssrc, bias + l * DIM, h_hi, h_lo, nt);
    }
  };

  if (combined) {
    run_graphs(x1, x2, ei1, ei2);
    k_pool<<<128, 256, 0, stream>>>(h_hi, h_lo, gw, gb, pool);
    k_pool<<<128, 256, 0, stream>>>(h_hi + size_t(NN) * DIM, h_lo + size_t(NN) * DIM,
                                    gw, gb, pool + 129);
  } else {
    run_graphs(x1, x1, ei1, ei1);
    k_pool<<<128, 256, 0, stream>>>(h_hi, h_lo, gw, gb, pool);
    run_graphs(x2, x2, ei2, ei2);
    k_pool<<<128, 256, 0, stream>>>(h_hi, h_lo, gw, gb, pool + 129);
  }
  k_mlp<<<1, 128, 0, stream>>>(pool, pool + 129, f1w, f1b, f2w, f2b, out);
}

// Round 11
// 705.068 us; speedup vs baseline: 1.0578x; 1.0257x over previous
//
#include <hip/hip_runtime.h>
#include <hip/hip_bf16.h>

#define NN 50000
#define NE 600000
#define DIM 128
#define VOCAB 30000
#define NEG 0.2f
#define GEPS 1e-16f

typedef __attribute__((ext_vector_type(8))) short bf16x8;
typedef __attribute__((ext_vector_type(4))) float f32x4;

__device__ __forceinline__ float leaky(float x) { return x > 0.f ? x : NEG * x; }

// bf16 split helpers (RNE)
__device__ __forceinline__ ushort f2bf(float f) {
  uint x = __float_as_uint(f);
  x += 0x7FFFu + ((x >> 16) & 1u);
  return (ushort)(x >> 16);
}
__device__ __forceinline__ float bf2f(ushort u) { return __uint_as_float(((uint)u) << 16); }

// ---------------- one-time: split embed into bf16 hi/lo ----------------
__global__ __launch_bounds__(256) void k_split(const float* __restrict__ src,
                                               ushort* __restrict__ hi,
                                               ushort* __restrict__ lo, int n4) {
  int i = blockIdx.x * 256 + threadIdx.x;
  if (i >= n4) return;
  float4 v = ((const float4*)src)[i];
  ushort4 h, l;
  h.x = f2bf(v.x); l.x = f2bf(v.x - bf2f(h.x));
  h.y = f2bf(v.y); l.y = f2bf(v.y - bf2f(h.y));
  h.z = f2bf(v.z); l.z = f2bf(v.z - bf2f(h.z));
  h.w = f2bf(v.w); l.w = f2bf(v.w - bf2f(h.w));
  ((ushort4*)hi)[i] = h;
  ((ushort4*)lo)[i] = l;
}

// ---------------- one-time: split W + pack into MFMA B-fragment order ------
__global__ __launch_bounds__(256) void k_packw(const float* __restrict__ W,
                                               ushort* __restrict__ wph,
                                               ushort* __restrict__ wpl) {
  int i = blockIdx.x * 256 + threadIdx.x;
  if (i >= 3 * 128 * 128) return;
  int ll = i >> 14, rem = i & 16383, k = rem >> 7, n = rem & 127;
  float v = W[i];
  ushort h = f2bf(v), l = f2bf(v - bf2f(h));
  int ct = n >> 4, ln = n & 15, kc = k >> 5, kr = k & 31;
  int lane = (kr >> 3) * 16 + ln, j = kr & 7;
  size_t dst = ((((size_t)ll * 8 + ct) * 4 + kc) * 64 + lane) * 8 + j;
  wph[dst] = h;
  wpl[dst] = l;
}

// ---------------- CSR build ----------------
__global__ __launch_bounds__(256) void k_count(const int* __restrict__ d1,
                                               const int* __restrict__ d2,
                                               int* __restrict__ cnt, int netot) {
  int e = blockIdx.x * blockDim.x + threadIdx.x;
  if (e >= netot) return;
  int dst = (e < NE) ? d1[e] : d2[e - NE] + NN;
  atomicAdd(&cnt[dst], 1);
}

__global__ __launch_bounds__(1024) void k_scan1(const int* __restrict__ cnt,
                                                int* __restrict__ roff,
                                                int* __restrict__ partials, int nn) {
  __shared__ int part[1024];
  const int t = threadIdx.x;
  const int idx = blockIdx.x * 1024 + t;
  int v = (idx < nn) ? cnt[idx] : 0;
  part[t] = v;
  __syncthreads();
  for (int off = 1; off < 1024; off <<= 1) {
    int x = (t >= off) ? part[t - off] : 0;
    __syncthreads();
    part[t] += x;
    __syncthreads();
  }
  if (idx < nn) roff[idx] = part[t] - v;
  if (t == 1023) partials[blockIdx.x] = part[1023];
}

__global__ __launch_bounds__(128) void k_scan2(int* __restrict__ partials, int nb) {
  __shared__ int part[128];
  const int t = threadIdx.x;
  int v = (t < nb) ? partials[t] : 0;
  part[t] = v;
  __syncthreads();
  for (int off = 1; off < 128; off <<= 1) {
    int x = (t >= off) ? part[t - off] : 0;
    __syncthreads();
    part[t] += x;
    __syncthreads();
  }
  if (t < nb) partials[t] = part[t] - v;
}

__global__ __launch_bounds__(1024) void k_scan3(int* __restrict__ roff,
                                                int* __restrict__ cur,
                                                const int* __restrict__ partials,
                                                int nn, int netot) {
  int idx = blockIdx.x * 1024 + threadIdx.x;
  if (idx < nn) {
    int v = roff[idx] + partials[blockIdx.x];
    roff[idx] = v;
    cur[idx] = v;
  }
  if (idx == 0) roff[nn] = netot;
}

__global__ __launch_bounds__(256) void k_fill(const int* __restrict__ s1,
                                              const int* __restrict__ d1,
                                              const int* __restrict__ s2,
                                              const int* __restrict__ d2,
                                              int* __restrict__ cur,
                                              int* __restrict__ ssrc, int netot) {
  int e = blockIdx.x * blockDim.x + threadIdx.x;
  if (e >= netot) return;
  int s, d;
  if (e < NE) { s = s1[e]; d = d1[e]; }
  else        { s = s2[e - NE] + NN; d = d2[e - NE] + NN; }
  int p = atomicAdd(&cur[d], 1);
  ssrc[p] = s;
}

// ---------------- linear via split-bf16 MFMA ----------------
__global__ __launch_bounds__(256) void k_linear(const ushort* __restrict__ Ahi,
                                                const ushort* __restrict__ Alo,
                                                const int* __restrict__ iA,
                                                const int* __restrict__ iB,
                                                const ushort* __restrict__ wph,
                                                const ushort* __restrict__ wpl,
                                                const float* __restrict__ a_src,
                                                const float* __restrict__ a_dst,
                                                float* __restrict__ hlin,
                                                float* __restrict__ asrc,
                                                float* __restrict__ adst, int ntot) {
  const int lane = threadIdx.x & 63;
  const int wv = threadIdx.x >> 6;
  const int m0 = blockIdx.x * 64 + wv * 16;
  const int ln = lane & 15, lh = lane >> 4;

  int m = m0 + ln;
  int mc = min(m, ntot - 1);
  int gr = mc;
  if (iA) gr = (mc < NN) ? iA[mc] : iB[mc - NN];
  const size_t abase = (size_t)gr * 128 + lh * 8;

  bf16x8 ah[4], al[4];
#pragma unroll
  for (int kc = 0; kc < 4; kc++) {
    ah[kc] = *(const bf16x8*)(Ahi + abase + kc * 32);
    al[kc] = *(const bf16x8*)(Alo + abase + kc * 32);
  }

  f32x4 acc[8];
#pragma unroll
  for (int ct = 0; ct < 8; ct++) acc[ct] = (f32x4){0.f, 0.f, 0.f, 0.f};

#pragma unroll
  for (int ct = 0; ct < 8; ct++) {
    const ushort* bh = wph + (size_t)ct * 2048 + lane * 8;
    const ushort* bl = wpl + (size_t)ct * 2048 + lane * 8;
#pragma unroll
    for (int kc = 0; kc < 4; kc++) {
      bf16x8 vh = *(const bf16x8*)(bh + kc * 512);
      bf16x8 vl = *(const bf16x8*)(bl + kc * 512);
      acc[ct] = __builtin_amdgcn_mfma_f32_16x16x32_bf16(ah[kc], vh, acc[ct], 0, 0, 0);
      acc[ct] = __builtin_amdgcn_mfma_f32_16x16x32_bf16(al[kc], vh, acc[ct], 0, 0, 0);
      acc[ct] = __builtin_amdgcn_mfma_f32_16x16x32_bf16(ah[kc], vl, acc[ct], 0, 0, 0);
    }
  }

  const int rbase = m0 + lh * 4;
#pragma unroll
  for (int r = 0; r < 4; r++) {
    int row = rbase + r;
    if (row < ntot) {
      float* dst = hlin + (size_t)row * 128 + ln;
#pragma unroll
      for (int ct = 0; ct < 8; ct++) dst[ct * 16] = acc[ct][r];
    }
  }

  float av[8], dv[8];
#pragma unroll
  for (int ct = 0; ct < 8; ct++) {
    av[ct] = a_src[ct * 16 + ln];
    dv[ct] = a_dst[ct * 16 + ln];
  }
#pragma unroll
  for (int r = 0; r < 4; r++) {
    float s0 = 0.f, s1 = 0.f, s2 = 0.f, s3 = 0.f;
    float d0 = 0.f, d1 = 0.f, d2 = 0.f, d3 = 0.f;
#pragma unroll
    for (int ct = 0; ct < 8; ct++) {
      float x = acc[ct][r];
      if ((ct >> 1) == 0) { s0 += x * av[ct]; d0 += x * dv[ct]; }
      else if ((ct >> 1) == 1) { s1 += x * av[ct]; d1 += x * dv[ct]; }
      else if ((ct >> 1) == 2) { s2 += x * av[ct]; d2 += x * dv[ct]; }
      else { s3 += x * av[ct]; d3 += x * dv[ct]; }
    }
#pragma unroll
    for (int off = 1; off < 16; off <<= 1) {
      s0 += __shfl_xor(s0, off); s1 += __shfl_xor(s1, off);
      s2 += __shfl_xor(s2, off); s3 += __shfl_xor(s3, off);
      d0 += __shfl_xor(d0, off); d1 += __shfl_xor(d1, off);
      d2 += __shfl_xor(d2, off); d3 += __shfl_xor(d3, off);
    }
    int row = rbase + r;
    if (ln == 0 && row < ntot) {
      ((float4*)asrc)[row] = make_float4(s0, s1, s2, s3);
      ((float4*)adst)[row] = make_float4(d0, d1, d2, d3);
    }
  }
}

// ---------------- aggregate (r8-best): one wave per dst node, pair-split ----
// lanes 0-31 even edge slots, 32-63 odd; each lane loads float4 (32 lanes =
// one 512B row, wave load = 2 rows). 8 batched pair-steps, loads issued
// before consumption. Softmax without max-subtraction; denom in PV loop.
// Outputs bf16 hi/lo for the next layer's MFMA.
__global__ __launch_bounds__(256) void k_aggregate(const float* __restrict__ hlin,
                                                   const float* __restrict__ asrcv,
                                                   const float* __restrict__ adstv,
                                                   const int* __restrict__ roff,
                                                   const int* __restrict__ ssrc,
                                                   const float* __restrict__ bias,
                                                   ushort* __restrict__ h_hi,
                                                   ushort* __restrict__ h_lo, int ntot) {
  const int lane = threadIdx.x & 63;
  const int n = blockIdx.x * 4 + (threadIdx.x >> 6);
  if (n >= ntot) return;
  const int p = lane >> 5;
  const int c = lane & 31;
  const int hc = c >> 3;
  const int sub = lane & 15;
  const int hs = lane >> 4;
  const int beg = roff[n], end = roff[n + 1];
  const int deg = end - beg;

  const float adh_hs = adstv[n * 4 + hs];
  const float pselfc = __expf(leaky(asrcv[n * 4 + hc] + adstv[n * 4 + hc]));

  float4 hv = ((const float4*)hlin)[(size_t)n * 32 + c];
  float4 acc;
  float dh;
  if (p == 0) {
    acc = make_float4(pselfc * hv.x, pselfc * hv.y, pselfc * hv.z, pselfc * hv.w);
    dh = pselfc;
  } else {
    acc = make_float4(0.f, 0.f, 0.f, 0.f);
    dh = 0.f;
  }

  for (int base = 0; base < deg; base += 16) {
    int cnt = deg - base; if (cnt > 16) cnt = 16;
    int s = n;
    float px = 0.f;
    if (sub < cnt) {
      s = ssrc[beg + base + sub];
      px = __expf(leaky(asrcv[s * 4 + hs] + adh_hs));
    }
    int sj[8]; float ex[8]; float4 ld[8];
#pragma unroll
    for (int jj = 0; jj < 8; jj++) {
      int e = 2 * jj + p;
      sj[jj] = __shfl(s, e);
      ex[jj] = __shfl(px, hc * 16 + e);
      ld[jj] = ((const float4*)hlin)[(size_t)sj[jj] * 32 + c];
    }
#pragma unroll
    for (int jj = 0; jj < 8; jj++) {
      acc.x += ex[jj] * ld[jj].x;
      acc.y += ex[jj] * ld[jj].y;
      acc.z += ex[jj] * ld[jj].z;
      acc.w += ex[jj] * ld[jj].w;
      dh += ex[jj];
    }
  }

  acc.x += __shfl_xor(acc.x, 32);
  acc.y += __shfl_xor(acc.y, 32);
  acc.z += __shfl_xor(acc.z, 32);
  acc.w += __shfl_xor(acc.w, 32);
  dh += __shfl_xor(dh, 32);

  float inv = 1.f / (dh + GEPS);
  float4 bv = ((const float4*)bias)[c];
  if (p == 0) {
    float4 o;
    o.x = fmaxf(acc.x * inv + bv.x, 0.f);
    o.y = fmaxf(acc.y * inv + bv.y, 0.f);
    o.z = fmaxf(acc.z * inv + bv.z, 0.f);
    o.w = fmaxf(acc.w * inv + bv.w, 0.f);
    ushort4 uh, ul;
    uh.x = f2bf(o.x); ul.x = f2bf(o.x - bf2f(uh.x));
    uh.y = f2bf(o.y); ul.y = f2bf(o.y - bf2f(uh.y));
    uh.z = f2bf(o.z); ul.z = f2bf(o.z - bf2f(uh.z));
    uh.w = f2bf(o.w); ul.w = f2bf(o.w - bf2f(uh.w));
    ((ushort4*)h_hi)[(size_t)n * 32 + c] = uh;
    ((ushort4*)h_lo)[(size_t)n * 32 + c] = ul;
  }
}

// ---------------- global attention pooling (reads bf16 hi/lo) ----------------
__global__ __launch_bounds__(256) void k_pool(const ushort* __restrict__ hh,
                                              const ushort* __restrict__ hl,
                                              const float* __restrict__ gate_w,
                                              const float* __restrict__ gate_b,
                                              float* __restrict__ acc_out) {
  const int lane = threadIdx.x & 63;
  const int widg = blockIdx.x * 4 + (threadIdx.x >> 6);
  const int nw = gridDim.x * 4;
  const float w0 = gate_w[lane * 2], w1 = gate_w[lane * 2 + 1];
  const float gb = gate_b[0];
  float acc0 = 0.f, acc1 = 0.f, se = 0.f;
  for (int n = widg; n < NN; n += nw) {
    ushort2 h2 = ((const ushort2*)hh)[(size_t)n * 64 + lane];
    ushort2 l2 = ((const ushort2*)hl)[(size_t)n * 64 + lane];
    float hx = bf2f(h2.x) + bf2f(l2.x);
    float hy = bf2f(h2.y) + bf2f(l2.y);
    float p = hx * w0 + hy * w1;
#pragma unroll
    for (int off = 1; off < 64; off <<= 1) p += __shfl_xor(p, off);
    float sg = 1.f / (1.f + __expf(-(p + gb)));
    float e = __expf(sg);
    se += e;
    acc0 += e * hx;
    acc1 += e * hy;
  }
  atomicAdd(&acc_out[lane * 2], acc0);
  atomicAdd(&acc_out[lane * 2 + 1], acc1);
  if (lane == 0) atomicAdd(&acc_out[128], se);
}

// ---------------- final MLP ----------------
__global__ __launch_bounds__(128) void k_mlp(const float* __restrict__ p1,
                                             const float* __restrict__ p2,
                                             const float* __restrict__ fc1_w,
                                             const float* __restrict__ fc1_b,
                                             const float* __restrict__ fc2_w,
                                             const float* __restrict__ fc2_b,
                                             float* __restrict__ out) {
  __shared__ float cat[256];
  __shared__ float red[2];
  const int t = threadIdx.x;
  cat[t] = p1[t] / p1[128];
  cat[128 + t] = p2[t] / p2[128];
  __syncthreads();
  float a = fc1_b[t];
  for (int k = 0; k < 256; k++) a += cat[k] * fc1_w[k * 128 + t];
  a = fmaxf(a, 0.f);
  float v = a * fc2_w[t];
#pragma unroll
  for (int off = 1; off < 64; off <<= 1) v += __shfl_xor(v, off);
  if ((t & 63) == 0) red[t >> 6] = v;
  __syncthreads();
  if (t == 0) out[0] = red[0] + red[1] + fc2_b[0];
}

extern "C" void kernel_launch(void* const* d_in, const int* in_sizes, int n_in,
                              void* d_out, int out_size, void* d_ws, size_t ws_size,
                              hipStream_t stream) {
  (void)in_sizes; (void)n_in; (void)out_size;
  const int* x1 = (const int*)d_in[0];
  const int* x2 = (const int*)d_in[1];
  const int* ei1 = (const int*)d_in[2];
  const int* ei2 = (const int*)d_in[3];
  const float* embed = (const float*)d_in[4];
  const float* W = (const float*)d_in[5];
  const float* attS = (const float*)d_in[6];
  const float* attD = (const float*)d_in[7];
  const float* bias = (const float*)d_in[8];
  const float* gw = (const float*)d_in[9];
  const float* gb = (const float*)d_in[10];
  const float* f1w = (const float*)d_in[11];
  const float* f1b = (const float*)d_in[12];
  const float* f2w = (const float*)d_in[13];
  const float* f2b = (const float*)d_in[14];
  float* out = (float*)d_out;

  auto req = [](int nt, int net) {
    size_t s = 0;
    auto pad = [&](size_t b) { s = (s + b + 255) & ~size_t(255); };
    pad(size_t(nt) * DIM * 2);        // h_hi
    pad(size_t(nt) * DIM * 2);        // h_lo
    pad(size_t(nt) * DIM * 4);        // h_lin
    pad(size_t(VOCAB) * DIM * 2);     // e_hi
    pad(size_t(VOCAB) * DIM * 2);     // e_lo
    pad(3 * 16384 * 2);               // wp_hi
    pad(3 * 16384 * 2);               // wp_lo
    pad(size_t(nt) * 16);             // asrc
    pad(size_t(nt) * 16);             // adst
    pad(size_t(nt + 1) * 4);          // roff
    pad(size_t(nt) * 4);              // cur
    pad(size_t(net) * 4);             // ssrc
    pad(128 * 4);                     // partials
    pad(2 * 129 * 4);                 // pool
    return s;
  };
  const bool combined = ws_size >= req(2 * NN, 2 * NE);
  const int nt = combined ? 2 * NN : NN;
  const int net = combined ? 2 * NE : NE;

  char* ws = (char*)d_ws;
  size_t off = 0;
  auto alloc = [&](size_t bytes) {
    void* p = ws + off;
    off = (off + bytes + 255) & ~size_t(255);
    return p;
  };
  ushort* h_hi = (ushort*)alloc(size_t(nt) * DIM * 2);
  ushort* h_lo = (ushort*)alloc(size_t(nt) * DIM * 2);
  float* h_lin = (float*)alloc(size_t(nt) * DIM * 4);
  ushort* e_hi = (ushort*)alloc(size_t(VOCAB) * DIM * 2);
  ushort* e_lo = (ushort*)alloc(size_t(VOCAB) * DIM * 2);
  ushort* wp_hi = (ushort*)alloc(3 * 16384 * 2);
  ushort* wp_lo = (ushort*)alloc(3 * 16384 * 2);
  float* asrc = (float*)alloc(size_t(nt) * 16);
  float* adst = (float*)alloc(size_t(nt) * 16);
  int* roff = (int*)alloc(size_t(nt + 1) * 4);
  int* cur = (int*)alloc(size_t(nt) * 4);
  int* ssrc = (int*)alloc(size_t(net) * 4);
  int* partials = (int*)alloc(128 * 4);
  float* pool = (float*)alloc(2 * 129 * 4);

  hipMemsetAsync(pool, 0, 2 * 129 * 4, stream);

  const int esplit4 = VOCAB * DIM / 4;
  k_split<<<(esplit4 + 255) / 256, 256, 0, stream>>>(embed, e_hi, e_lo, esplit4);
  k_packw<<<(3 * 128 * 128 + 255) / 256, 256, 0, stream>>>(W, wp_hi, wp_lo);

  const int nb = (nt + 1023) / 1024;
  const int lgrid = (nt + 63) / 64;

  auto run_graphs = [&](const int* xA, const int* xB, const int* eA, const int* eB) {
    hipMemsetAsync(cur, 0, size_t(nt) * 4, stream);
    k_count<<<(net + 255) / 256, 256, 0, stream>>>(eA + NE, eB + NE, cur, net);
    k_scan1<<<nb, 1024, 0, stream>>>(cur, roff, partials, nt);
    k_scan2<<<1, 128, 0, stream>>>(partials, nb);
    k_scan3<<<nb, 1024, 0, stream>>>(roff, cur, partials, nt, net);
    k_fill<<<(net + 255) / 256, 256, 0, stream>>>(eA, eA + NE, eB, eB + NE, cur, ssrc, net);
    for (int l = 0; l < 3; ++l) {
      if (l == 0) {
        k_linear<<<lgrid, 256, 0, stream>>>(
            e_hi, e_lo, xA, xB, wp_hi, wp_lo, attS, attD, h_lin, asrc, adst, nt);
      } else {
        k_linear<<<lgrid, 256, 0, stream>>>(
            h_hi, h_lo, nullptr, nullptr, wp_hi + l * 16384, wp_lo + l * 16384,
            attS + l * DIM, attD + l * DIM, h_lin, asrc, adst, nt);
      }
      k_aggregate<<<(nt + 3) / 4, 256, 0, stream>>>(
          h_lin, asrc, adst, roff, ssrc, bias + l * DIM, h_hi, h_lo, nt);
    }
  };

  if (combined) {
    run_graphs(x1, x2, ei1, ei2);
    k_pool<<<128, 256, 0, stream>>>(h_hi, h_lo, gw, gb, pool);
    k_pool<<<128, 256, 0, stream>>>(h_hi + size_t(NN) * DIM, h_lo + size_t(NN) * DIM,
                                    gw, gb, pool + 129);
  } else {
    run_graphs(x1, x1, ei1, ei1);
    k_pool<<<128, 256, 0, stream>>>(h_hi, h_lo, gw, gb, pool);
    run_graphs(x2, x2, ei2, ei2);
    k_pool<<<128, 256, 0, stream>>>(h_hi, h_lo, gw, gb, pool + 129);
  }
  k_mlp<<<1, 128, 0, stream>>>(pool, pool + 129, f1w, f1b, f2w, f2b, out);
}

// Round 12
// 588.863 us; speedup vs baseline: 1.2665x; 1.1973x over previous
//
#include <hip/hip_runtime.h>
#include <hip/hip_bf16.h>

#define NN 50000
#define NE 600000
#define DIM 128
#define VOCAB 30000
#define NEG 0.2f
#define GEPS 1e-16f

typedef __attribute__((ext_vector_type(8))) short bf16x8;
typedef __attribute__((ext_vector_type(4))) float f32x4;

__device__ __forceinline__ float leaky(float x) { return x > 0.f ? x : NEG * x; }

// bf16 split helpers (RNE)
__device__ __forceinline__ ushort f2bf(float f) {
  uint x = __float_as_uint(f);
  x += 0x7FFFu + ((x >> 16) & 1u);
  return (ushort)(x >> 16);
}
__device__ __forceinline__ float bf2f(ushort u) { return __uint_as_float(((uint)u) << 16); }

// ---------------- one-time: split embed into bf16 hi/lo ----------------
__global__ __launch_bounds__(256) void k_split(const float* __restrict__ src,
                                               ushort* __restrict__ hi,
                                               ushort* __restrict__ lo, int n4) {
  int i = blockIdx.x * 256 + threadIdx.x;
  if (i >= n4) return;
  float4 v = ((const float4*)src)[i];
  ushort4 h, l;
  h.x = f2bf(v.x); l.x = f2bf(v.x - bf2f(h.x));
  h.y = f2bf(v.y); l.y = f2bf(v.y - bf2f(h.y));
  h.z = f2bf(v.z); l.z = f2bf(v.z - bf2f(h.z));
  h.w = f2bf(v.w); l.w = f2bf(v.w - bf2f(h.w));
  ((ushort4*)hi)[i] = h;
  ((ushort4*)lo)[i] = l;
}

// ---------------- one-time: split W + pack into MFMA B-fragment order ------
__global__ __launch_bounds__(256) void k_packw(const float* __restrict__ W,
                                               ushort* __restrict__ wph,
                                               ushort* __restrict__ wpl) {
  int i = blockIdx.x * 256 + threadIdx.x;
  if (i >= 3 * 128 * 128) return;
  int ll = i >> 14, rem = i & 16383, k = rem >> 7, n = rem & 127;
  float v = W[i];
  ushort h = f2bf(v), l = f2bf(v - bf2f(h));
  int ct = n >> 4, ln = n & 15, kc = k >> 5, kr = k & 31;
  int lane = (kr >> 3) * 16 + ln, j = kr & 7;
  size_t dst = ((((size_t)ll * 8 + ct) * 4 + kc) * 64 + lane) * 8 + j;
  wph[dst] = h;
  wpl[dst] = l;
}

// ---------------- CSR build ----------------
__global__ __launch_bounds__(256) void k_count(const int* __restrict__ d1,
                                               const int* __restrict__ d2,
                                               int* __restrict__ cnt, int netot) {
  int e = blockIdx.x * blockDim.x + threadIdx.x;
  if (e >= netot) return;
  int dst = (e < NE) ? d1[e] : d2[e - NE] + NN;
  atomicAdd(&cnt[dst], 1);
}

__global__ __launch_bounds__(1024) void k_scan1(const int* __restrict__ cnt,
                                                int* __restrict__ roff,
                                                int* __restrict__ partials, int nn) {
  __shared__ int part[1024];
  const int t = threadIdx.x;
  const int idx = blockIdx.x * 1024 + t;
  int v = (idx < nn) ? cnt[idx] : 0;
  part[t] = v;
  __syncthreads();
  for (int off = 1; off < 1024; off <<= 1) {
    int x = (t >= off) ? part[t - off] : 0;
    __syncthreads();
    part[t] += x;
    __syncthreads();
  }
  if (idx < nn) roff[idx] = part[t] - v;
  if (t == 1023) partials[blockIdx.x] = part[1023];
}

__global__ __launch_bounds__(128) void k_scan2(int* __restrict__ partials, int nb) {
  __shared__ int part[128];
  const int t = threadIdx.x;
  int v = (t < nb) ? partials[t] : 0;
  part[t] = v;
  __syncthreads();
  for (int off = 1; off < 128; off <<= 1) {
    int x = (t >= off) ? part[t - off] : 0;
    __syncthreads();
    part[t] += x;
    __syncthreads();
  }
  if (t < nb) partials[t] = part[t] - v;
}

__global__ __launch_bounds__(1024) void k_scan3(int* __restrict__ roff,
                                                int* __restrict__ cur,
                                                const int* __restrict__ partials,
                                                int nn, int netot) {
  int idx = blockIdx.x * 1024 + threadIdx.x;
  if (idx < nn) {
    int v = roff[idx] + partials[blockIdx.x];
    roff[idx] = v;
    cur[idx] = v;
  }
  if (idx == 0) roff[nn] = netot;
}

__global__ __launch_bounds__(256) void k_fill(const int* __restrict__ s1,
                                              const int* __restrict__ d1,
                                              const int* __restrict__ s2,
                                              const int* __restrict__ d2,
                                              int* __restrict__ cur,
                                              int* __restrict__ ssrc, int netot) {
  int e = blockIdx.x * blockDim.x + threadIdx.x;
  if (e >= netot) return;
  int s, d;
  if (e < NE) { s = s1[e]; d = d1[e]; }
  else        { s = s2[e - NE] + NN; d = d2[e - NE] + NN; }
  int p = atomicAdd(&cur[d], 1);
  ssrc[p] = s;
}

// ---------------- linear via split-bf16 MFMA ----------------
// hlin is now stored as bf16 (256B rows) -- halves the aggregate's gather
// traffic; attention dots asrc/adst stay fp32-exact from the accumulators.
__global__ __launch_bounds__(256) void k_linear(const ushort* __restrict__ Ahi,
                                                const ushort* __restrict__ Alo,
                                                const int* __restrict__ iA,
                                                const int* __restrict__ iB,
                                                const ushort* __restrict__ wph,
                                                const ushort* __restrict__ wpl,
                                                const float* __restrict__ a_src,
                                                const float* __restrict__ a_dst,
                                                ushort* __restrict__ hlinb,
                                                float* __restrict__ asrc,
                                                float* __restrict__ adst, int ntot) {
  const int lane = threadIdx.x & 63;
  const int wv = threadIdx.x >> 6;
  const int m0 = blockIdx.x * 64 + wv * 16;
  const int ln = lane & 15, lh = lane >> 4;

  int m = m0 + ln;
  int mc = min(m, ntot - 1);
  int gr = mc;
  if (iA) gr = (mc < NN) ? iA[mc] : iB[mc - NN];
  const size_t abase = (size_t)gr * 128 + lh * 8;

  bf16x8 ah[4], al[4];
#pragma unroll
  for (int kc = 0; kc < 4; kc++) {
    ah[kc] = *(const bf16x8*)(Ahi + abase + kc * 32);
    al[kc] = *(const bf16x8*)(Alo + abase + kc * 32);
  }

  f32x4 acc[8];
#pragma unroll
  for (int ct = 0; ct < 8; ct++) acc[ct] = (f32x4){0.f, 0.f, 0.f, 0.f};

#pragma unroll
  for (int ct = 0; ct < 8; ct++) {
    const ushort* bh = wph + (size_t)ct * 2048 + lane * 8;
    const ushort* bl = wpl + (size_t)ct * 2048 + lane * 8;
#pragma unroll
    for (int kc = 0; kc < 4; kc++) {
      bf16x8 vh = *(const bf16x8*)(bh + kc * 512);
      bf16x8 vl = *(const bf16x8*)(bl + kc * 512);
      acc[ct] = __builtin_amdgcn_mfma_f32_16x16x32_bf16(ah[kc], vh, acc[ct], 0, 0, 0);
      acc[ct] = __builtin_amdgcn_mfma_f32_16x16x32_bf16(al[kc], vh, acc[ct], 0, 0, 0);
      acc[ct] = __builtin_amdgcn_mfma_f32_16x16x32_bf16(ah[kc], vl, acc[ct], 0, 0, 0);
    }
  }

  const int rbase = m0 + lh * 4;
#pragma unroll
  for (int r = 0; r < 4; r++) {
    int row = rbase + r;
    if (row < ntot) {
      ushort* dst = hlinb + (size_t)row * 128 + ln;
#pragma unroll
      for (int ct = 0; ct < 8; ct++) dst[ct * 16] = f2bf(acc[ct][r]);
    }
  }

  float av[8], dv[8];
#pragma unroll
  for (int ct = 0; ct < 8; ct++) {
    av[ct] = a_src[ct * 16 + ln];
    dv[ct] = a_dst[ct * 16 + ln];
  }
#pragma unroll
  for (int r = 0; r < 4; r++) {
    float s0 = 0.f, s1 = 0.f, s2 = 0.f, s3 = 0.f;
    float d0 = 0.f, d1 = 0.f, d2 = 0.f, d3 = 0.f;
#pragma unroll
    for (int ct = 0; ct < 8; ct++) {
      float x = acc[ct][r];
      if ((ct >> 1) == 0) { s0 += x * av[ct]; d0 += x * dv[ct]; }
      else if ((ct >> 1) == 1) { s1 += x * av[ct]; d1 += x * dv[ct]; }
      else if ((ct >> 1) == 2) { s2 += x * av[ct]; d2 += x * dv[ct]; }
      else { s3 += x * av[ct]; d3 += x * dv[ct]; }
    }
#pragma unroll
    for (int off = 1; off < 16; off <<= 1) {
      s0 += __shfl_xor(s0, off); s1 += __shfl_xor(s1, off);
      s2 += __shfl_xor(s2, off); s3 += __shfl_xor(s3, off);
      d0 += __shfl_xor(d0, off); d1 += __shfl_xor(d1, off);
      d2 += __shfl_xor(d2, off); d3 += __shfl_xor(d3, off);
    }
    int row = rbase + r;
    if (ln == 0 && row < ntot) {
      ((float4*)asrc)[row] = make_float4(s0, s1, s2, s3);
      ((float4*)adst)[row] = make_float4(d0, d1, d2, d3);
    }
  }
}

// ---------------- aggregate (r8 structure, bf16 gather rows) ----------------
// lanes 0-31 even edge slots, 32-63 odd; each lane loads ushort4 (4 bf16,
// 8B; 32 lanes = one 256B row, wave load = 2 rows). 8 batched pair-steps,
// loads issued before consumption. Softmax without max-subtraction.
__global__ __launch_bounds__(256) void k_aggregate(const ushort* __restrict__ hlinb,
                                                   const float* __restrict__ asrcv,
                                                   const float* __restrict__ adstv,
                                                   const int* __restrict__ roff,
                                                   const int* __restrict__ ssrc,
                                                   const float* __restrict__ bias,
                                                   ushort* __restrict__ h_hi,
                                                   ushort* __restrict__ h_lo, int ntot) {
  const int lane = threadIdx.x & 63;
  const int n = blockIdx.x * 4 + (threadIdx.x >> 6);
  if (n >= ntot) return;
  const int p = lane >> 5;
  const int c = lane & 31;
  const int hc = c >> 3;
  const int sub = lane & 15;
  const int hs = lane >> 4;
  const int beg = roff[n], end = roff[n + 1];
  const int deg = end - beg;

  const float adh_hs = adstv[n * 4 + hs];
  const float pselfc = __expf(leaky(asrcv[n * 4 + hc] + adstv[n * 4 + hc]));

  ushort4 hb = ((const ushort4*)hlinb)[(size_t)n * 32 + c];
  float4 hv = make_float4(bf2f(hb.x), bf2f(hb.y), bf2f(hb.z), bf2f(hb.w));
  float4 acc;
  float dh;
  if (p == 0) {
    acc = make_float4(pselfc * hv.x, pselfc * hv.y, pselfc * hv.z, pselfc * hv.w);
    dh = pselfc;
  } else {
    acc = make_float4(0.f, 0.f, 0.f, 0.f);
    dh = 0.f;
  }

  for (int base = 0; base < deg; base += 16) {
    int cnt = deg - base; if (cnt > 16) cnt = 16;
    int s = n;
    float px = 0.f;
    if (sub < cnt) {
      s = ssrc[beg + base + sub];
      px = __expf(leaky(asrcv[s * 4 + hs] + adh_hs));
    }
    int sj[8]; float ex[8]; ushort4 ld[8];
#pragma unroll
    for (int jj = 0; jj < 8; jj++) {
      int e = 2 * jj + p;
      sj[jj] = __shfl(s, e);
      ex[jj] = __shfl(px, hc * 16 + e);
      ld[jj] = ((const ushort4*)hlinb)[(size_t)sj[jj] * 32 + c];
    }
#pragma unroll
    for (int jj = 0; jj < 8; jj++) {
      acc.x += ex[jj] * bf2f(ld[jj].x);
      acc.y += ex[jj] * bf2f(ld[jj].y);
      acc.z += ex[jj] * bf2f(ld[jj].z);
      acc.w += ex[jj] * bf2f(ld[jj].w);
      dh += ex[jj];
    }
  }

  acc.x += __shfl_xor(acc.x, 32);
  acc.y += __shfl_xor(acc.y, 32);
  acc.z += __shfl_xor(acc.z, 32);
  acc.w += __shfl_xor(acc.w, 32);
  dh += __shfl_xor(dh, 32);

  float inv = 1.f / (dh + GEPS);
  float4 bv = ((const float4*)bias)[c];
  if (p == 0) {
    float4 o;
    o.x = fmaxf(acc.x * inv + bv.x, 0.f);
    o.y = fmaxf(acc.y * inv + bv.y, 0.f);
    o.z = fmaxf(acc.z * inv + bv.z, 0.f);
    o.w = fmaxf(acc.w * inv + bv.w, 0.f);
    ushort4 uh, ul;
    uh.x = f2bf(o.x); ul.x = f2bf(o.x - bf2f(uh.x));
    uh.y = f2bf(o.y); ul.y = f2bf(o.y - bf2f(uh.y));
    uh.z = f2bf(o.z); ul.z = f2bf(o.z - bf2f(uh.z));
    uh.w = f2bf(o.w); ul.w = f2bf(o.w - bf2f(uh.w));
    ((ushort4*)h_hi)[(size_t)n * 32 + c] = uh;
    ((ushort4*)h_lo)[(size_t)n * 32 + c] = ul;
  }
}

// ---------------- global attention pooling (reads bf16 hi/lo) ----------------
__global__ __launch_bounds__(256) void k_pool(const ushort* __restrict__ hh,
                                              const ushort* __restrict__ hl,
                                              const float* __restrict__ gate_w,
                                              const float* __restrict__ gate_b,
                                              float* __restrict__ acc_out) {
  const int lane = threadIdx.x & 63;
  const int widg = blockIdx.x * 4 + (threadIdx.x >> 6);
  const int nw = gridDim.x * 4;
  const float w0 = gate_w[lane * 2], w1 = gate_w[lane * 2 + 1];
  const float gb = gate_b[0];
  float acc0 = 0.f, acc1 = 0.f, se = 0.f;
  for (int n = widg; n < NN; n += nw) {
    ushort2 h2 = ((const ushort2*)hh)[(size_t)n * 64 + lane];
    ushort2 l2 = ((const ushort2*)hl)[(size_t)n * 64 + lane];
    float hx = bf2f(h2.x) + bf2f(l2.x);
    float hy = bf2f(h2.y) + bf2f(l2.y);
    float p = hx * w0 + hy * w1;
#pragma unroll
    for (int off = 1; off < 64; off <<= 1) p += __shfl_xor(p, off);
    float sg = 1.f / (1.f + __expf(-(p + gb)));
    float e = __expf(sg);
    se += e;
    acc0 += e * hx;
    acc1 += e * hy;
  }
  atomicAdd(&acc_out[lane * 2], acc0);
  atomicAdd(&acc_out[lane * 2 + 1], acc1);
  if (lane == 0) atomicAdd(&acc_out[128], se);
}

// ---------------- final MLP ----------------
__global__ __launch_bounds__(128) void k_mlp(const float* __restrict__ p1,
                                             const float* __restrict__ p2,
                                             const float* __restrict__ fc1_w,
                                             const float* __restrict__ fc1_b,
                                             const float* __restrict__ fc2_w,
                                             const float* __restrict__ fc2_b,
                                             float* __restrict__ out) {
  __shared__ float cat[256];
  __shared__ float red[2];
  const int t = threadIdx.x;
  cat[t] = p1[t] / p1[128];
  cat[128 + t] = p2[t] / p2[128];
  __syncthreads();
  float a = fc1_b[t];
  for (int k = 0; k < 256; k++) a += cat[k] * fc1_w[k * 128 + t];
  a = fmaxf(a, 0.f);
  float v = a * fc2_w[t];
#pragma unroll
  for (int off = 1; off < 64; off <<= 1) v += __shfl_xor(v, off);
  if ((t & 63) == 0) red[t >> 6] = v;
  __syncthreads();
  if (t == 0) out[0] = red[0] + red[1] + fc2_b[0];
}

extern "C" void kernel_launch(void* const* d_in, const int* in_sizes, int n_in,
                              void* d_out, int out_size, void* d_ws, size_t ws_size,
                              hipStream_t stream) {
  (void)in_sizes; (void)n_in; (void)out_size;
  const int* x1 = (const int*)d_in[0];
  const int* x2 = (const int*)d_in[1];
  const int* ei1 = (const int*)d_in[2];
  const int* ei2 = (const int*)d_in[3];
  const float* embed = (const float*)d_in[4];
  const float* W = (const float*)d_in[5];
  const float* attS = (const float*)d_in[6];
  const float* attD = (const float*)d_in[7];
  const float* bias = (const float*)d_in[8];
  const float* gw = (const float*)d_in[9];
  const float* gb = (const float*)d_in[10];
  const float* f1w = (const float*)d_in[11];
  const float* f1b = (const float*)d_in[12];
  const float* f2w = (const float*)d_in[13];
  const float* f2b = (const float*)d_in[14];
  float* out = (float*)d_out;

  auto req = [](int nt, int net) {
    size_t s = 0;
    auto pad = [&](size_t b) { s = (s + b + 255) & ~size_t(255); };
    pad(size_t(nt) * DIM * 2);        // h_hi
    pad(size_t(nt) * DIM * 2);        // h_lo
    pad(size_t(nt) * DIM * 2);        // hlinb (bf16)
    pad(size_t(VOCAB) * DIM * 2);     // e_hi
    pad(size_t(VOCAB) * DIM * 2);     // e_lo
    pad(3 * 16384 * 2);               // wp_hi
    pad(3 * 16384 * 2);               // wp_lo
    pad(size_t(nt) * 16);             // asrc
    pad(size_t(nt) * 16);             // adst
    pad(size_t(nt + 1) * 4);          // roff
    pad(size_t(nt) * 4);              // cur
    pad(size_t(net) * 4);             // ssrc
    pad(128 * 4);                     // partials
    pad(2 * 129 * 4);                 // pool
    return s;
  };
  const bool combined = ws_size >= req(2 * NN, 2 * NE);
  const int nt = combined ? 2 * NN : NN;
  const int net = combined ? 2 * NE : NE;

  char* ws = (char*)d_ws;
  size_t off = 0;
  auto alloc = [&](size_t bytes) {
    void* p = ws + off;
    off = (off + bytes + 255) & ~size_t(255);
    return p;
  };
  ushort* h_hi = (ushort*)alloc(size_t(nt) * DIM * 2);
  ushort* h_lo = (ushort*)alloc(size_t(nt) * DIM * 2);
  ushort* hlinb = (ushort*)alloc(size_t(nt) * DIM * 2);
  ushort* e_hi = (ushort*)alloc(size_t(VOCAB) * DIM * 2);
  ushort* e_lo = (ushort*)alloc(size_t(VOCAB) * DIM * 2);
  ushort* wp_hi = (ushort*)alloc(3 * 16384 * 2);
  ushort* wp_lo = (ushort*)alloc(3 * 16384 * 2);
  float* asrc = (float*)alloc(size_t(nt) * 16);
  float* adst = (float*)alloc(size_t(nt) * 16);
  int* roff = (int*)alloc(size_t(nt + 1) * 4);
  int* cur = (int*)alloc(size_t(nt) * 4);
  int* ssrc = (int*)alloc(size_t(net) * 4);
  int* partials = (int*)alloc(128 * 4);
  float* pool = (float*)alloc(2 * 129 * 4);

  hipMemsetAsync(pool, 0, 2 * 129 * 4, stream);

  const int esplit4 = VOCAB * DIM / 4;
  k_split<<<(esplit4 + 255) / 256, 256, 0, stream>>>(embed, e_hi, e_lo, esplit4);
  k_packw<<<(3 * 128 * 128 + 255) / 256, 256, 0, stream>>>(W, wp_hi, wp_lo);

  const int nb = (nt + 1023) / 1024;
  const int lgrid = (nt + 63) / 64;

  auto run_graphs = [&](const int* xA, const int* xB, const int* eA, const int* eB) {
    hipMemsetAsync(cur, 0, size_t(nt) * 4, stream);
    k_count<<<(net + 255) / 256, 256, 0, stream>>>(eA + NE, eB + NE, cur, net);
    k_scan1<<<nb, 1024, 0, stream>>>(cur, roff, partials, nt);
    k_scan2<<<1, 128, 0, stream>>>(partials, nb);
    k_scan3<<<nb, 1024, 0, stream>>>(roff, cur, partials, nt, net);
    k_fill<<<(net + 255) / 256, 256, 0, stream>>>(eA, eA + NE, eB, eB + NE, cur, ssrc, net);
    for (int l = 0; l < 3; ++l) {
      if (l == 0) {
        k_linear<<<lgrid, 256, 0, stream>>>(
            e_hi, e_lo, xA, xB, wp_hi, wp_lo, attS, attD, hlinb, asrc, adst, nt);
      } else {
        k_linear<<<lgrid, 256, 0, stream>>>(
            h_hi, h_lo, nullptr, nullptr, wp_hi + l * 16384, wp_lo + l * 16384,
            attS + l * DIM, attD + l * DIM, hlinb, asrc, adst, nt);
      }
      k_aggregate<<<(nt + 3) / 4, 256, 0, stream>>>(
          hlinb, asrc, adst, roff, ssrc, bias + l * DIM, h_hi, h_lo, nt);
    }
  };

  if (combined) {
    run_graphs(x1, x2, ei1, ei2);
    k_pool<<<128, 256, 0, stream>>>(h_hi, h_lo, gw, gb, pool);
    k_pool<<<128, 256, 0, stream>>>(h_hi + size_t(NN) * DIM, h_lo + size_t(NN) * DIM,
                                    gw, gb, pool + 129);
  } else {
    run_graphs(x1, x1, ei1, ei1);
    k_pool<<<128, 256, 0, stream>>>(h_hi, h_lo, gw, gb, pool);
    run_graphs(x2, x2, ei2, ei2);
    k_pool<<<128, 256, 0, stream>>>(h_hi, h_lo, gw, gb, pool + 129);
  }
  k_mlp<<<1, 128, 0, stream>>>(pool, pool + 129, f1w, f1b, f2w, f2b, out);
}

// Round 13
// 547.965 us; speedup vs baseline: 1.3611x; 1.0746x over previous
//
#include <hip/hip_runtime.h>
#include <hip/hip_bf16.h>

#define NN 50000
#define NE 600000
#define DIM 128
#define VOCAB 30000
#define NEG 0.2f
#define GEPS 1e-16f
#define CAP 64

typedef __attribute__((ext_vector_type(8))) short bf16x8;
typedef __attribute__((ext_vector_type(4))) float f32x4;

__device__ __forceinline__ float leaky(float x) { return x > 0.f ? x : NEG * x; }

// bf16 split helpers (RNE)
__device__ __forceinline__ ushort f2bf(float f) {
  uint x = __float_as_uint(f);
  x += 0x7FFFu + ((x >> 16) & 1u);
  return (ushort)(x >> 16);
}
__device__ __forceinline__ float bf2f(ushort u) { return __uint_as_float(((uint)u) << 16); }

// ---------------- one-time: split embed into bf16 hi/lo ----------------
__global__ __launch_bounds__(256) void k_split(const float* __restrict__ src,
                                               ushort* __restrict__ hi,
                                               ushort* __restrict__ lo, int n4) {
  int i = blockIdx.x * 256 + threadIdx.x;
  if (i >= n4) return;
  float4 v = ((const float4*)src)[i];
  ushort4 h, l;
  h.x = f2bf(v.x); l.x = f2bf(v.x - bf2f(h.x));
  h.y = f2bf(v.y); l.y = f2bf(v.y - bf2f(h.y));
  h.z = f2bf(v.z); l.z = f2bf(v.z - bf2f(h.z));
  h.w = f2bf(v.w); l.w = f2bf(v.w - bf2f(h.w));
  ((ushort4*)hi)[i] = h;
  ((ushort4*)lo)[i] = l;
}

// ---------------- one-time: split W + pack into MFMA B-fragment order ------
__global__ __launch_bounds__(256) void k_packw(const float* __restrict__ W,
                                               ushort* __restrict__ wph,
                                               ushort* __restrict__ wpl) {
  int i = blockIdx.x * 256 + threadIdx.x;
  if (i >= 3 * 128 * 128) return;
  int ll = i >> 14, rem = i & 16383, k = rem >> 7, n = rem & 127;
  float v = W[i];
  ushort h = f2bf(v), l = f2bf(v - bf2f(h));
  int ct = n >> 4, ln = n & 15, kc = k >> 5, kr = k & 31;
  int lane = (kr >> 3) * 16 + ln, j = kr & 7;
  size_t dst = ((((size_t)ll * 8 + ct) * 4 + kc) * 64 + lane) * 8 + j;
  wph[dst] = h;
  wpl[dst] = l;
}

// ---------------- bucketed CSR: single pass, no scan ----------------
// ssrc[d*CAP + r] = src, r = atomicAdd(cur[d]); CAP=64 >> max degree
// (Poisson(12): P(deg>=48) ~ 5e-21 per node) so the clamp never triggers.
__global__ __launch_bounds__(256) void k_bucket(const int* __restrict__ s1,
                                                const int* __restrict__ d1,
                                                const int* __restrict__ s2,
                                                const int* __restrict__ d2,
                                                int* __restrict__ cur,
                                                int* __restrict__ ssrc, int netot) {
  int e = blockIdx.x * blockDim.x + threadIdx.x;
  if (e >= netot) return;
  int s, d;
  if (e < NE) { s = s1[e]; d = d1[e]; }
  else        { s = s2[e - NE] + NN; d = d2[e - NE] + NN; }
  int r = atomicAdd(&cur[d], 1);
  if (r < CAP) ssrc[((size_t)d << 6) + r] = s;
}

// ---------------- linear via split-bf16 MFMA ----------------
__global__ __launch_bounds__(256) void k_linear(const ushort* __restrict__ Ahi,
                                                const ushort* __restrict__ Alo,
                                                const int* __restrict__ iA,
                                                const int* __restrict__ iB,
                                                const ushort* __restrict__ wph,
                                                const ushort* __restrict__ wpl,
                                                const float* __restrict__ a_src,
                                                const float* __restrict__ a_dst,
                                                ushort* __restrict__ hlinb,
                                                float* __restrict__ asrc,
                                                float* __restrict__ adst, int ntot) {
  const int lane = threadIdx.x & 63;
  const int wv = threadIdx.x >> 6;
  const int m0 = blockIdx.x * 64 + wv * 16;
  const int ln = lane & 15, lh = lane >> 4;

  int m = m0 + ln;
  int mc = min(m, ntot - 1);
  int gr = mc;
  if (iA) gr = (mc < NN) ? iA[mc] : iB[mc - NN];
  const size_t abase = (size_t)gr * 128 + lh * 8;

  bf16x8 ah[4], al[4];
#pragma unroll
  for (int kc = 0; kc < 4; kc++) {
    ah[kc] = *(const bf16x8*)(Ahi + abase + kc * 32);
    al[kc] = *(const bf16x8*)(Alo + abase + kc * 32);
  }

  f32x4 acc[8];
#pragma unroll
  for (int ct = 0; ct < 8; ct++) acc[ct] = (f32x4){0.f, 0.f, 0.f, 0.f};

#pragma unroll
  for (int ct = 0; ct < 8; ct++) {
    const ushort* bh = wph + (size_t)ct * 2048 + lane * 8;
    const ushort* bl = wpl + (size_t)ct * 2048 + lane * 8;
#pragma unroll
    for (int kc = 0; kc < 4; kc++) {
      bf16x8 vh = *(const bf16x8*)(bh + kc * 512);
      bf16x8 vl = *(const bf16x8*)(bl + kc * 512);
      acc[ct] = __builtin_amdgcn_mfma_f32_16x16x32_bf16(ah[kc], vh, acc[ct], 0, 0, 0);
      acc[ct] = __builtin_amdgcn_mfma_f32_16x16x32_bf16(al[kc], vh, acc[ct], 0, 0, 0);
      acc[ct] = __builtin_amdgcn_mfma_f32_16x16x32_bf16(ah[kc], vl, acc[ct], 0, 0, 0);
    }
  }

  const int rbase = m0 + lh * 4;
#pragma unroll
  for (int r = 0; r < 4; r++) {
    int row = rbase + r;
    if (row < ntot) {
      ushort* dst = hlinb + (size_t)row * 128 + ln;
#pragma unroll
      for (int ct = 0; ct < 8; ct++) dst[ct * 16] = f2bf(acc[ct][r]);
    }
  }

  float av[8], dv[8];
#pragma unroll
  for (int ct = 0; ct < 8; ct++) {
    av[ct] = a_src[ct * 16 + ln];
    dv[ct] = a_dst[ct * 16 + ln];
  }
#pragma unroll
  for (int r = 0; r < 4; r++) {
    float s0 = 0.f, s1 = 0.f, s2 = 0.f, s3 = 0.f;
    float d0 = 0.f, d1 = 0.f, d2 = 0.f, d3 = 0.f;
#pragma unroll
    for (int ct = 0; ct < 8; ct++) {
      float x = acc[ct][r];
      if ((ct >> 1) == 0) { s0 += x * av[ct]; d0 += x * dv[ct]; }
      else if ((ct >> 1) == 1) { s1 += x * av[ct]; d1 += x * dv[ct]; }
      else if ((ct >> 1) == 2) { s2 += x * av[ct]; d2 += x * dv[ct]; }
      else { s3 += x * av[ct]; d3 += x * dv[ct]; }
    }
#pragma unroll
    for (int off = 1; off < 16; off <<= 1) {
      s0 += __shfl_xor(s0, off); s1 += __shfl_xor(s1, off);
      s2 += __shfl_xor(s2, off); s3 += __shfl_xor(s3, off);
      d0 += __shfl_xor(d0, off); d1 += __shfl_xor(d1, off);
      d2 += __shfl_xor(d2, off); d3 += __shfl_xor(d3, off);
    }
    int row = rbase + r;
    if (ln == 0 && row < ntot) {
      ((float4*)asrc)[row] = make_float4(s0, s1, s2, s3);
      ((float4*)adst)[row] = make_float4(d0, d1, d2, d3);
    }
  }
}

// ---------------- aggregate (r8 structure, bf16 rows, bucketed edges) -------
__global__ __launch_bounds__(256) void k_aggregate(const ushort* __restrict__ hlinb,
                                                   const float* __restrict__ asrcv,
                                                   const float* __restrict__ adstv,
                                                   const int* __restrict__ cnt,
                                                   const int* __restrict__ ssrc,
                                                   const float* __restrict__ bias,
                                                   ushort* __restrict__ h_hi,
                                                   ushort* __restrict__ h_lo, int ntot) {
  const int lane = threadIdx.x & 63;
  const int n = blockIdx.x * 4 + (threadIdx.x >> 6);
  if (n >= ntot) return;
  const int p = lane >> 5;
  const int c = lane & 31;
  const int hc = c >> 3;
  const int sub = lane & 15;
  const int hs = lane >> 4;
  const size_t beg = (size_t)n << 6;
  const int deg = min(cnt[n], CAP);

  const float adh_hs = adstv[n * 4 + hs];
  const float pselfc = __expf(leaky(asrcv[n * 4 + hc] + adstv[n * 4 + hc]));

  ushort4 hb = ((const ushort4*)hlinb)[(size_t)n * 32 + c];
  float4 hv = make_float4(bf2f(hb.x), bf2f(hb.y), bf2f(hb.z), bf2f(hb.w));
  float4 acc;
  float dh;
  if (p == 0) {
    acc = make_float4(pselfc * hv.x, pselfc * hv.y, pselfc * hv.z, pselfc * hv.w);
    dh = pselfc;
  } else {
    acc = make_float4(0.f, 0.f, 0.f, 0.f);
    dh = 0.f;
  }

  for (int base = 0; base < deg; base += 16) {
    int cnt16 = deg - base; if (cnt16 > 16) cnt16 = 16;
    int s = n;
    float px = 0.f;
    if (sub < cnt16) {
      s = ssrc[beg + base + sub];
      px = __expf(leaky(asrcv[s * 4 + hs] + adh_hs));
    }
    int sj[8]; float ex[8]; ushort4 ld[8];
#pragma unroll
    for (int jj = 0; jj < 8; jj++) {
      int e = 2 * jj + p;
      sj[jj] = __shfl(s, e);
      ex[jj] = __shfl(px, hc * 16 + e);
      ld[jj] = ((const ushort4*)hlinb)[(size_t)sj[jj] * 32 + c];
    }
#pragma unroll
    for (int jj = 0; jj < 8; jj++) {
      acc.x += ex[jj] * bf2f(ld[jj].x);
      acc.y += ex[jj] * bf2f(ld[jj].y);
      acc.z += ex[jj] * bf2f(ld[jj].z);
      acc.w += ex[jj] * bf2f(ld[jj].w);
      dh += ex[jj];
    }
  }

  acc.x += __shfl_xor(acc.x, 32);
  acc.y += __shfl_xor(acc.y, 32);
  acc.z += __shfl_xor(acc.z, 32);
  acc.w += __shfl_xor(acc.w, 32);
  dh += __shfl_xor(dh, 32);

  float inv = 1.f / (dh + GEPS);
  float4 bv = ((const float4*)bias)[c];
  if (p == 0) {
    float4 o;
    o.x = fmaxf(acc.x * inv + bv.x, 0.f);
    o.y = fmaxf(acc.y * inv + bv.y, 0.f);
    o.z = fmaxf(acc.z * inv + bv.z, 0.f);
    o.w = fmaxf(acc.w * inv + bv.w, 0.f);
    ushort4 uh, ul;
    uh.x = f2bf(o.x); ul.x = f2bf(o.x - bf2f(uh.x));
    uh.y = f2bf(o.y); ul.y = f2bf(o.y - bf2f(uh.y));
    uh.z = f2bf(o.z); ul.z = f2bf(o.z - bf2f(uh.z));
    uh.w = f2bf(o.w); ul.w = f2bf(o.w - bf2f(uh.w));
    ((ushort4*)h_hi)[(size_t)n * 32 + c] = uh;
    ((ushort4*)h_lo)[(size_t)n * 32 + c] = ul;
  }
}

// ---------------- global attention pooling (reads bf16 hi/lo) ----------------
__global__ __launch_bounds__(256) void k_pool(const ushort* __restrict__ hh,
                                              const ushort* __restrict__ hl,
                                              const float* __restrict__ gate_w,
                                              const float* __restrict__ gate_b,
                                              float* __restrict__ acc_out) {
  const int lane = threadIdx.x & 63;
  const int widg = blockIdx.x * 4 + (threadIdx.x >> 6);
  const int nw = gridDim.x * 4;
  const float w0 = gate_w[lane * 2], w1 = gate_w[lane * 2 + 1];
  const float gb = gate_b[0];
  float acc0 = 0.f, acc1 = 0.f, se = 0.f;
  for (int n = widg; n < NN; n += nw) {
    ushort2 h2 = ((const ushort2*)hh)[(size_t)n * 64 + lane];
    ushort2 l2 = ((const ushort2*)hl)[(size_t)n * 64 + lane];
    float hx = bf2f(h2.x) + bf2f(l2.x);
    float hy = bf2f(h2.y) + bf2f(l2.y);
    float p = hx * w0 + hy * w1;
#pragma unroll
    for (int off = 1; off < 64; off <<= 1) p += __shfl_xor(p, off);
    float sg = 1.f / (1.f + __expf(-(p + gb)));
    float e = __expf(sg);
    se += e;
    acc0 += e * hx;
    acc1 += e * hy;
  }
  atomicAdd(&acc_out[lane * 2], acc0);
  atomicAdd(&acc_out[lane * 2 + 1], acc1);
  if (lane == 0) atomicAdd(&acc_out[128], se);
}

// ---------------- final MLP ----------------
__global__ __launch_bounds__(128) void k_mlp(const float* __restrict__ p1,
                                             const float* __restrict__ p2,
                                             const float* __restrict__ fc1_w,
                                             const float* __restrict__ fc1_b,
                                             const float* __restrict__ fc2_w,
                                             const float* __restrict__ fc2_b,
                                             float* __restrict__ out) {
  __shared__ float cat[256];
  __shared__ float red[2];
  const int t = threadIdx.x;
  cat[t] = p1[t] / p1[128];
  cat[128 + t] = p2[t] / p2[128];
  __syncthreads();
  float a = fc1_b[t];
  for (int k = 0; k < 256; k++) a += cat[k] * fc1_w[k * 128 + t];
  a = fmaxf(a, 0.f);
  float v = a * fc2_w[t];
#pragma unroll
  for (int off = 1; off < 64; off <<= 1) v += __shfl_xor(v, off);
  if ((t & 63) == 0) red[t >> 6] = v;
  __syncthreads();
  if (t == 0) out[0] = red[0] + red[1] + fc2_b[0];
}

extern "C" void kernel_launch(void* const* d_in, const int* in_sizes, int n_in,
                              void* d_out, int out_size, void* d_ws, size_t ws_size,
                              hipStream_t stream) {
  (void)in_sizes; (void)n_in; (void)out_size;
  const int* x1 = (const int*)d_in[0];
  const int* x2 = (const int*)d_in[1];
  const int* ei1 = (const int*)d_in[2];
  const int* ei2 = (const int*)d_in[3];
  const float* embed = (const float*)d_in[4];
  const float* W = (const float*)d_in[5];
  const float* attS = (const float*)d_in[6];
  const float* attD = (const float*)d_in[7];
  const float* bias = (const float*)d_in[8];
  const float* gw = (const float*)d_in[9];
  const float* gb = (const float*)d_in[10];
  const float* f1w = (const float*)d_in[11];
  const float* f1b = (const float*)d_in[12];
  const float* f2w = (const float*)d_in[13];
  const float* f2b = (const float*)d_in[14];
  float* out = (float*)d_out;

  auto req = [](int nt) {
    size_t s = 0;
    auto pad = [&](size_t b) { s = (s + b + 255) & ~size_t(255); };
    pad(size_t(nt) * DIM * 2);        // h_hi
    pad(size_t(nt) * DIM * 2);        // h_lo
    pad(size_t(nt) * DIM * 2);        // hlinb (bf16)
    pad(size_t(VOCAB) * DIM * 2);     // e_hi
    pad(size_t(VOCAB) * DIM * 2);     // e_lo
    pad(3 * 16384 * 2);               // wp_hi
    pad(3 * 16384 * 2);               // wp_lo
    pad(size_t(nt) * 16);             // asrc
    pad(size_t(nt) * 16);             // adst
    pad(size_t(nt) * 4);              // cur
    pad(size_t(nt) * CAP * 4);        // ssrc buckets
    pad(2 * 129 * 4);                 // pool
    return s;
  };
  const bool combined = ws_size >= req(2 * NN);
  const int nt = combined ? 2 * NN : NN;
  const int net = combined ? 2 * NE : NE;

  char* ws = (char*)d_ws;
  size_t off = 0;
  auto alloc = [&](size_t bytes) {
    void* p = ws + off;
    off = (off + bytes + 255) & ~size_t(255);
    return p;
  };
  ushort* h_hi = (ushort*)alloc(size_t(nt) * DIM * 2);
  ushort* h_lo = (ushort*)alloc(size_t(nt) * DIM * 2);
  ushort* hlinb = (ushort*)alloc(size_t(nt) * DIM * 2);
  ushort* e_hi = (ushort*)alloc(size_t(VOCAB) * DIM * 2);
  ushort* e_lo = (ushort*)alloc(size_t(VOCAB) * DIM * 2);
  ushort* wp_hi = (ushort*)alloc(3 * 16384 * 2);
  ushort* wp_lo = (ushort*)alloc(3 * 16384 * 2);
  float* asrc = (float*)alloc(size_t(nt) * 16);
  float* adst = (float*)alloc(size_t(nt) * 16);
  int* cur = (int*)alloc(size_t(nt) * 4);
  int* ssrc = (int*)alloc(size_t(nt) * CAP * 4);
  float* pool = (float*)alloc(2 * 129 * 4);

  hipMemsetAsync(pool, 0, 2 * 129 * 4, stream);

  const int esplit4 = VOCAB * DIM / 4;
  k_split<<<(esplit4 + 255) / 256, 256, 0, stream>>>(embed, e_hi, e_lo, esplit4);
  k_packw<<<(3 * 128 * 128 + 255) / 256, 256, 0, stream>>>(W, wp_hi, wp_lo);

  const int lgrid = (nt + 63) / 64;

  auto run_graphs = [&](const int* xA, const int* xB, const int* eA, const int* eB) {
    hipMemsetAsync(cur, 0, size_t(nt) * 4, stream);
    k_bucket<<<(net + 255) / 256, 256, 0, stream>>>(eA, eA + NE, eB, eB + NE, cur, ssrc, net);
    for (int l = 0; l < 3; ++l) {
      if (l == 0) {
        k_linear<<<lgrid, 256, 0, stream>>>(
            e_hi, e_lo, xA, xB, wp_hi, wp_lo, attS, attD, hlinb, asrc, adst, nt);
      } else {
        k_linear<<<lgrid, 256, 0, stream>>>(
            h_hi, h_lo, nullptr, nullptr, wp_hi + l * 16384, wp_lo + l * 16384,
            attS + l * DIM, attD + l * DIM, hlinb, asrc, adst, nt);
      }
      k_aggregate<<<(nt + 3) / 4, 256, 0, stream>>>(
          hlinb, asrc, adst, cur, ssrc, bias + l * DIM, h_hi, h_lo, nt);
    }
  };

  if (combined) {
    run_graphs(x1, x2, ei1, ei2);
    k_pool<<<128, 256, 0, stream>>>(h_hi, h_lo, gw, gb, pool);
    k_pool<<<128, 256, 0, stream>>>(h_hi + size_t(NN) * DIM, h_lo + size_t(NN) * DIM,
                                    gw, gb, pool + 129);
  } else {
    run_graphs(x1, x1, ei1, ei1);
    k_pool<<<128, 256, 0, stream>>>(h_hi, h_lo, gw, gb, pool);
    run_graphs(x2, x2, ei2, ei2);
    k_pool<<<128, 256, 0, stream>>>(h_hi, h_lo, gw, gb, pool + 129);
  }
  k_mlp<<<1, 128, 0, stream>>>(pool, pool + 129, f1w, f1b, f2w, f2b, out);
}

// Round 14
// 517.282 us; speedup vs baseline: 1.4418x; 1.0593x over previous
//
#include <hip/hip_runtime.h>
#include <hip/hip_bf16.h>

#define NN 50000
#define NE 600000
#define DIM 128
#define VOCAB 30000
#define NEG 0.2f
#define GEPS 1e-16f
#define CAP 64

typedef __attribute__((ext_vector_type(8))) short bf16x8;
typedef __attribute__((ext_vector_type(4))) float f32x4;

__device__ __forceinline__ float leaky(float x) { return x > 0.f ? x : NEG * x; }

// bf16 split helpers (RNE)
__device__ __forceinline__ ushort f2bf(float f) {
  uint x = __float_as_uint(f);
  x += 0x7FFFu + ((x >> 16) & 1u);
  return (ushort)(x >> 16);
}
__device__ __forceinline__ float bf2f(ushort u) { return __uint_as_float(((uint)u) << 16); }

// ---------------- one-time: split embed into bf16 hi/lo ----------------
__global__ __launch_bounds__(256) void k_split(const float* __restrict__ src,
                                               ushort* __restrict__ hi,
                                               ushort* __restrict__ lo, int n4) {
  int i = blockIdx.x * 256 + threadIdx.x;
  if (i >= n4) return;
  float4 v = ((const float4*)src)[i];
  ushort4 h, l;
  h.x = f2bf(v.x); l.x = f2bf(v.x - bf2f(h.x));
  h.y = f2bf(v.y); l.y = f2bf(v.y - bf2f(h.y));
  h.z = f2bf(v.z); l.z = f2bf(v.z - bf2f(h.z));
  h.w = f2bf(v.w); l.w = f2bf(v.w - bf2f(h.w));
  ((ushort4*)hi)[i] = h;
  ((ushort4*)lo)[i] = l;
}

// ---------------- one-time: split W + pack into MFMA B-fragment order ------
__global__ __launch_bounds__(256) void k_packw(const float* __restrict__ W,
                                               ushort* __restrict__ wph,
                                               ushort* __restrict__ wpl) {
  int i = blockIdx.x * 256 + threadIdx.x;
  if (i >= 3 * 128 * 128) return;
  int ll = i >> 14, rem = i & 16383, k = rem >> 7, n = rem & 127;
  float v = W[i];
  ushort h = f2bf(v), l = f2bf(v - bf2f(h));
  int ct = n >> 4, ln = n & 15, kc = k >> 5, kr = k & 31;
  int lane = (kr >> 3) * 16 + ln, j = kr & 7;
  size_t dst = ((((size_t)ll * 8 + ct) * 4 + kc) * 64 + lane) * 8 + j;
  wph[dst] = h;
  wpl[dst] = l;
}

// ---------------- bucketed CSR, XCD-partitioned ----------------
// Block bid owns dst partition (bid&7); partition bucket slice (3.2 MB) and
// its counters stay resident in that XCD's 4 MB L2 (round-robin blockIdx->XCD
// heuristic; correctness independent of mapping). Edges are read 8x
// (coalesced, L2/L3-absorbed) but each is processed by exactly one block.
__global__ __launch_bounds__(256) void k_bucket(const int* __restrict__ s1,
                                                const int* __restrict__ d1,
                                                const int* __restrict__ s2,
                                                const int* __restrict__ d2,
                                                int* __restrict__ cur,
                                                int* __restrict__ ssrc,
                                                int netot, int nt) {
  const int part = blockIdx.x & 7;
  const int chunk = blockIdx.x >> 3;
  const int nchunk = gridDim.x >> 3;
  const int psz = nt >> 3;              // nt divisible by 8 (100000 or 50000? 50000/8=6250 ok)
  const int lo = part * psz;
  const int hi = (part == 7) ? nt : lo + psz;
  for (int e = chunk * 256 + threadIdx.x; e < netot; e += nchunk * 256) {
    int s, d;
    if (e < NE) { s = s1[e]; d = d1[e]; }
    else        { s = s2[e - NE] + NN; d = d2[e - NE] + NN; }
    if (d >= lo && d < hi) {
      int r = atomicAdd(&cur[d], 1);
      if (r < CAP) ssrc[((size_t)d << 6) + r] = s;
    }
  }
}

// ---------------- linear via split-bf16 MFMA ----------------
__global__ __launch_bounds__(256) void k_linear(const ushort* __restrict__ Ahi,
                                                const ushort* __restrict__ Alo,
                                                const int* __restrict__ iA,
                                                const int* __restrict__ iB,
                                                const ushort* __restrict__ wph,
                                                const ushort* __restrict__ wpl,
                                                const float* __restrict__ a_src,
                                                const float* __restrict__ a_dst,
                                                ushort* __restrict__ hlinb,
                                                float* __restrict__ asrc,
                                                float* __restrict__ adst, int ntot) {
  const int lane = threadIdx.x & 63;
  const int wv = threadIdx.x >> 6;
  const int m0 = blockIdx.x * 64 + wv * 16;
  const int ln = lane & 15, lh = lane >> 4;

  int m = m0 + ln;
  int mc = min(m, ntot - 1);
  int gr = mc;
  if (iA) gr = (mc < NN) ? iA[mc] : iB[mc - NN];
  const size_t abase = (size_t)gr * 128 + lh * 8;

  bf16x8 ah[4], al[4];
#pragma unroll
  for (int kc = 0; kc < 4; kc++) {
    ah[kc] = *(const bf16x8*)(Ahi + abase + kc * 32);
    al[kc] = *(const bf16x8*)(Alo + abase + kc * 32);
  }

  f32x4 acc[8];
#pragma unroll
  for (int ct = 0; ct < 8; ct++) acc[ct] = (f32x4){0.f, 0.f, 0.f, 0.f};

#pragma unroll
  for (int ct = 0; ct < 8; ct++) {
    const ushort* bh = wph + (size_t)ct * 2048 + lane * 8;
    const ushort* bl = wpl + (size_t)ct * 2048 + lane * 8;
#pragma unroll
    for (int kc = 0; kc < 4; kc++) {
      bf16x8 vh = *(const bf16x8*)(bh + kc * 512);
      bf16x8 vl = *(const bf16x8*)(bl + kc * 512);
      acc[ct] = __builtin_amdgcn_mfma_f32_16x16x32_bf16(ah[kc], vh, acc[ct], 0, 0, 0);
      acc[ct] = __builtin_amdgcn_mfma_f32_16x16x32_bf16(al[kc], vh, acc[ct], 0, 0, 0);
      acc[ct] = __builtin_amdgcn_mfma_f32_16x16x32_bf16(ah[kc], vl, acc[ct], 0, 0, 0);
    }
  }

  const int rbase = m0 + lh * 4;
#pragma unroll
  for (int r = 0; r < 4; r++) {
    int row = rbase + r;
    if (row < ntot) {
      ushort* dst = hlinb + (size_t)row * 128 + ln;
#pragma unroll
      for (int ct = 0; ct < 8; ct++) dst[ct * 16] = f2bf(acc[ct][r]);
    }
  }

  float av[8], dv[8];
#pragma unroll
  for (int ct = 0; ct < 8; ct++) {
    av[ct] = a_src[ct * 16 + ln];
    dv[ct] = a_dst[ct * 16 + ln];
  }
#pragma unroll
  for (int r = 0; r < 4; r++) {
    float s0 = 0.f, s1 = 0.f, s2 = 0.f, s3 = 0.f;
    float d0 = 0.f, d1 = 0.f, d2 = 0.f, d3 = 0.f;
#pragma unroll
    for (int ct = 0; ct < 8; ct++) {
      float x = acc[ct][r];
      if ((ct >> 1) == 0) { s0 += x * av[ct]; d0 += x * dv[ct]; }
      else if ((ct >> 1) == 1) { s1 += x * av[ct]; d1 += x * dv[ct]; }
      else if ((ct >> 1) == 2) { s2 += x * av[ct]; d2 += x * dv[ct]; }
      else { s3 += x * av[ct]; d3 += x * dv[ct]; }
    }
#pragma unroll
    for (int off = 1; off < 16; off <<= 1) {
      s0 += __shfl_xor(s0, off); s1 += __shfl_xor(s1, off);
      s2 += __shfl_xor(s2, off); s3 += __shfl_xor(s3, off);
      d0 += __shfl_xor(d0, off); d1 += __shfl_xor(d1, off);
      d2 += __shfl_xor(d2, off); d3 += __shfl_xor(d3, off);
    }
    int row = rbase + r;
    if (ln == 0 && row < ntot) {
      ((float4*)asrc)[row] = make_float4(s0, s1, s2, s3);
      ((float4*)adst)[row] = make_float4(d0, d1, d2, d3);
    }
  }
}

// ---------------- aggregate (r8 structure, bf16 rows, bucketed edges) -------
__global__ __launch_bounds__(256) void k_aggregate(const ushort* __restrict__ hlinb,
                                                   const float* __restrict__ asrcv,
                                                   const float* __restrict__ adstv,
                                                   const int* __restrict__ cnt,
                                                   const int* __restrict__ ssrc,
                                                   const float* __restrict__ bias,
                                                   ushort* __restrict__ h_hi,
                                                   ushort* __restrict__ h_lo, int ntot) {
  const int lane = threadIdx.x & 63;
  const int n = blockIdx.x * 4 + (threadIdx.x >> 6);
  if (n >= ntot) return;
  const int p = lane >> 5;
  const int c = lane & 31;
  const int hc = c >> 3;
  const int sub = lane & 15;
  const int hs = lane >> 4;
  const size_t beg = (size_t)n << 6;
  const int deg = min(cnt[n], CAP);

  const float adh_hs = adstv[n * 4 + hs];
  const float pselfc = __expf(leaky(asrcv[n * 4 + hc] + adstv[n * 4 + hc]));

  ushort4 hb = ((const ushort4*)hlinb)[(size_t)n * 32 + c];
  float4 hv = make_float4(bf2f(hb.x), bf2f(hb.y), bf2f(hb.z), bf2f(hb.w));
  float4 acc;
  float dh;
  if (p == 0) {
    acc = make_float4(pselfc * hv.x, pselfc * hv.y, pselfc * hv.z, pselfc * hv.w);
    dh = pselfc;
  } else {
    acc = make_float4(0.f, 0.f, 0.f, 0.f);
    dh = 0.f;
  }

  for (int base = 0; base < deg; base += 16) {
    int cnt16 = deg - base; if (cnt16 > 16) cnt16 = 16;
    int s = n;
    float px = 0.f;
    if (sub < cnt16) {
      s = ssrc[beg + base + sub];
      px = __expf(leaky(asrcv[s * 4 + hs] + adh_hs));
    }
    int sj[8]; float ex[8]; ushort4 ld[8];
#pragma unroll
    for (int jj = 0; jj < 8; jj++) {
      int e = 2 * jj + p;
      sj[jj] = __shfl(s, e);
      ex[jj] = __shfl(px, hc * 16 + e);
      ld[jj] = ((const ushort4*)hlinb)[(size_t)sj[jj] * 32 + c];
    }
#pragma unroll
    for (int jj = 0; jj < 8; jj++) {
      acc.x += ex[jj] * bf2f(ld[jj].x);
      acc.y += ex[jj] * bf2f(ld[jj].y);
      acc.z += ex[jj] * bf2f(ld[jj].z);
      acc.w += ex[jj] * bf2f(ld[jj].w);
      dh += ex[jj];
    }
  }

  acc.x += __shfl_xor(acc.x, 32);
  acc.y += __shfl_xor(acc.y, 32);
  acc.z += __shfl_xor(acc.z, 32);
  acc.w += __shfl_xor(acc.w, 32);
  dh += __shfl_xor(dh, 32);

  float inv = 1.f / (dh + GEPS);
  float4 bv = ((const float4*)bias)[c];
  if (p == 0) {
    float4 o;
    o.x = fmaxf(acc.x * inv + bv.x, 0.f);
    o.y = fmaxf(acc.y * inv + bv.y, 0.f);
    o.z = fmaxf(acc.z * inv + bv.z, 0.f);
    o.w = fmaxf(acc.w * inv + bv.w, 0.f);
    ushort4 uh, ul;
    uh.x = f2bf(o.x); ul.x = f2bf(o.x - bf2f(uh.x));
    uh.y = f2bf(o.y); ul.y = f2bf(o.y - bf2f(uh.y));
    uh.z = f2bf(o.z); ul.z = f2bf(o.z - bf2f(uh.z));
    uh.w = f2bf(o.w); ul.w = f2bf(o.w - bf2f(uh.w));
    ((ushort4*)h_hi)[(size_t)n * 32 + c] = uh;
    ((ushort4*)h_lo)[(size_t)n * 32 + c] = ul;
  }
}

// ---------------- global attention pooling (reads bf16 hi/lo) ----------------
__global__ __launch_bounds__(256) void k_pool(const ushort* __restrict__ hh,
                                              const ushort* __restrict__ hl,
                                              const float* __restrict__ gate_w,
                                              const float* __restrict__ gate_b,
                                              float* __restrict__ acc_out) {
  const int lane = threadIdx.x & 63;
  const int widg = blockIdx.x * 4 + (threadIdx.x >> 6);
  const int nw = gridDim.x * 4;
  const float w0 = gate_w[lane * 2], w1 = gate_w[lane * 2 + 1];
  const float gb = gate_b[0];
  float acc0 = 0.f, acc1 = 0.f, se = 0.f;
  for (int n = widg; n < NN; n += nw) {
    ushort2 h2 = ((const ushort2*)hh)[(size_t)n * 64 + lane];
    ushort2 l2 = ((const ushort2*)hl)[(size_t)n * 64 + lane];
    float hx = bf2f(h2.x) + bf2f(l2.x);
    float hy = bf2f(h2.y) + bf2f(l2.y);
    float p = hx * w0 + hy * w1;
#pragma unroll
    for (int off = 1; off < 64; off <<= 1) p += __shfl_xor(p, off);
    float sg = 1.f / (1.f + __expf(-(p + gb)));
    float e = __expf(sg);
    se += e;
    acc0 += e * hx;
    acc1 += e * hy;
  }
  atomicAdd(&acc_out[lane * 2], acc0);
  atomicAdd(&acc_out[lane * 2 + 1], acc1);
  if (lane == 0) atomicAdd(&acc_out[128], se);
}

// ---------------- final MLP ----------------
__global__ __launch_bounds__(128) void k_mlp(const float* __restrict__ p1,
                                             const float* __restrict__ p2,
                                             const float* __restrict__ fc1_w,
                                             const float* __restrict__ fc1_b,
                                             const float* __restrict__ fc2_w,
                                             const float* __restrict__ fc2_b,
                                             float* __restrict__ out) {
  __shared__ float cat[256];
  __shared__ float red[2];
  const int t = threadIdx.x;
  cat[t] = p1[t] / p1[128];
  cat[128 + t] = p2[t] / p2[128];
  __syncthreads();
  float a = fc1_b[t];
  for (int k = 0; k < 256; k++) a += cat[k] * fc1_w[k * 128 + t];
  a = fmaxf(a, 0.f);
  float v = a * fc2_w[t];
#pragma unroll
  for (int off = 1; off < 64; off <<= 1) v += __shfl_xor(v, off);
  if ((t & 63) == 0) red[t >> 6] = v;
  __syncthreads();
  if (t == 0) out[0] = red[0] + red[1] + fc2_b[0];
}

extern "C" void kernel_launch(void* const* d_in, const int* in_sizes, int n_in,
                              void* d_out, int out_size, void* d_ws, size_t ws_size,
                              hipStream_t stream) {
  (void)in_sizes; (void)n_in; (void)out_size;
  const int* x1 = (const int*)d_in[0];
  const int* x2 = (const int*)d_in[1];
  const int* ei1 = (const int*)d_in[2];
  const int* ei2 = (const int*)d_in[3];
  const float* embed = (const float*)d_in[4];
  const float* W = (const float*)d_in[5];
  const float* attS = (const float*)d_in[6];
  const float* attD = (const float*)d_in[7];
  const float* bias = (const float*)d_in[8];
  const float* gw = (const float*)d_in[9];
  const float* gb = (const float*)d_in[10];
  const float* f1w = (const float*)d_in[11];
  const float* f1b = (const float*)d_in[12];
  const float* f2w = (const float*)d_in[13];
  const float* f2b = (const float*)d_in[14];
  float* out = (float*)d_out;

  auto req = [](int nt) {
    size_t s = 0;
    auto pad = [&](size_t b) { s = (s + b + 255) & ~size_t(255); };
    pad(size_t(nt) * DIM * 2);        // h_hi
    pad(size_t(nt) * DIM * 2);        // h_lo
    pad(size_t(nt) * DIM * 2);        // hlinb (bf16)
    pad(size_t(VOCAB) * DIM * 2);     // e_hi
    pad(size_t(VOCAB) * DIM * 2);     // e_lo
    pad(3 * 16384 * 2);               // wp_hi
    pad(3 * 16384 * 2);               // wp_lo
    pad(size_t(nt) * 16);             // asrc
    pad(size_t(nt) * 16);             // adst
    pad(size_t(nt) * 4);              // cur
    pad(size_t(nt) * CAP * 4);        // ssrc buckets
    pad(2 * 129 * 4);                 // pool
    return s;
  };
  const bool combined = ws_size >= req(2 * NN);
  const int nt = combined ? 2 * NN : NN;
  const int net = combined ? 2 * NE : NE;

  char* ws = (char*)d_ws;
  size_t off = 0;
  auto alloc = [&](size_t bytes) {
    void* p = ws + off;
    off = (off + bytes + 255) & ~size_t(255);
    return p;
  };
  ushort* h_hi = (ushort*)alloc(size_t(nt) * DIM * 2);
  ushort* h_lo = (ushort*)alloc(size_t(nt) * DIM * 2);
  ushort* hlinb = (ushort*)alloc(size_t(nt) * DIM * 2);
  ushort* e_hi = (ushort*)alloc(size_t(VOCAB) * DIM * 2);
  ushort* e_lo = (ushort*)alloc(size_t(VOCAB) * DIM * 2);
  ushort* wp_hi = (ushort*)alloc(3 * 16384 * 2);
  ushort* wp_lo = (ushort*)alloc(3 * 16384 * 2);
  float* asrc = (float*)alloc(size_t(nt) * 16);
  float* adst = (float*)alloc(size_t(nt) * 16);
  int* cur = (int*)alloc(size_t(nt) * 4);
  int* ssrc = (int*)alloc(size_t(nt) * CAP * 4);
  float* pool = (float*)alloc(2 * 129 * 4);

  hipMemsetAsync(pool, 0, 2 * 129 * 4, stream);

  const int esplit4 = VOCAB * DIM / 4;
  k_split<<<(esplit4 + 255) / 256, 256, 0, stream>>>(embed, e_hi, e_lo, esplit4);
  k_packw<<<(3 * 128 * 128 + 255) / 256, 256, 0, stream>>>(W, wp_hi, wp_lo);

  const int lgrid = (nt + 63) / 64;
  const int nchunk = (net + 256 * 8 - 1) / (256 * 8);  // ~8 iters/block

  auto run_graphs = [&](const int* xA, const int* xB, const int* eA, const int* eB) {
    hipMemsetAsync(cur, 0, size_t(nt) * 4, stream);
    k_bucket<<<nchunk * 8, 256, 0, stream>>>(eA, eA + NE, eB, eB + NE, cur, ssrc, net, nt);
    for (int l = 0; l < 3; ++l) {
      if (l == 0) {
        k_linear<<<lgrid, 256, 0, stream>>>(
            e_hi, e_lo, xA, xB, wp_hi, wp_lo, attS, attD, hlinb, asrc, adst, nt);
      } else {
        k_linear<<<lgrid, 256, 0, stream>>>(
            h_hi, h_lo, nullptr, nullptr, wp_hi + l * 16384, wp_lo + l * 16384,
            attS + l * DIM, attD + l * DIM, hlinb, asrc, adst, nt);
      }
      k_aggregate<<<(nt + 3) / 4, 256, 0, stream>>>(
          hlinb, asrc, adst, cur, ssrc, bias + l * DIM, h_hi, h_lo, nt);
    }
  };

  if (combined) {
    run_graphs(x1, x2, ei1, ei2);
    k_pool<<<128, 256, 0, stream>>>(h_hi, h_lo, gw, gb, pool);
    k_pool<<<128, 256, 0, stream>>>(h_hi + size_t(NN) * DIM, h_lo + size_t(NN) * DIM,
                                    gw, gb, pool + 129);
  } else {
    run_graphs(x1, x1, ei1, ei1);
    k_pool<<<128, 256, 0, stream>>>(h_hi, h_lo, gw, gb, pool);
    run_graphs(x2, x2, ei2, ei2);
    k_pool<<<128, 256, 0, stream>>>(h_hi, h_lo, gw, gb, pool + 129);
  }
  k_mlp<<<1, 128, 0, stream>>>(pool, pool + 129, f1w, f1b, f2w, f2b, out);
}

// Round 15
// 424.501 us; speedup vs baseline: 1.7569x; 1.2186x over previous
//
#include <hip/hip_runtime.h>
#include <hip/hip_bf16.h>

#define NN 50000
#define NE 600000
#define DIM 128
#define VOCAB 30000
#define NEG 0.2f
#define GEPS 1e-16f
#define CAP 64

typedef __attribute__((ext_vector_type(8))) short bf16x8;
typedef __attribute__((ext_vector_type(4))) float f32x4;

__device__ __forceinline__ float leaky(float x) { return x > 0.f ? x : NEG * x; }

// bf16 split helpers (RNE)
__device__ __forceinline__ ushort f2bf(float f) {
  uint x = __float_as_uint(f);
  x += 0x7FFFu + ((x >> 16) & 1u);
  return (ushort)(x >> 16);
}
__device__ __forceinline__ float bf2f(ushort u) { return __uint_as_float(((uint)u) << 16); }

// ---------------- one-time: split embed into bf16 hi/lo ----------------
__global__ __launch_bounds__(256) void k_split(const float* __restrict__ src,
                                               ushort* __restrict__ hi,
                                               ushort* __restrict__ lo, int n4) {
  int i = blockIdx.x * 256 + threadIdx.x;
  if (i >= n4) return;
  float4 v = ((const float4*)src)[i];
  ushort4 h, l;
  h.x = f2bf(v.x); l.x = f2bf(v.x - bf2f(h.x));
  h.y = f2bf(v.y); l.y = f2bf(v.y - bf2f(h.y));
  h.z = f2bf(v.z); l.z = f2bf(v.z - bf2f(h.z));
  h.w = f2bf(v.w); l.w = f2bf(v.w - bf2f(h.w));
  ((ushort4*)hi)[i] = h;
  ((ushort4*)lo)[i] = l;
}

// ---------------- one-time: split W + pack into MFMA B-fragment order ------
__global__ __launch_bounds__(256) void k_packw(const float* __restrict__ W,
                                               ushort* __restrict__ wph,
                                               ushort* __restrict__ wpl) {
  int i = blockIdx.x * 256 + threadIdx.x;
  if (i >= 3 * 128 * 128) return;
  int ll = i >> 14, rem = i & 16383, k = rem >> 7, n = rem & 127;
  float v = W[i];
  ushort h = f2bf(v), l = f2bf(v - bf2f(h));
  int ct = n >> 4, ln = n & 15, kc = k >> 5, kr = k & 31;
  int lane = (kr >> 3) * 16 + ln, j = kr & 7;
  size_t dst = ((((size_t)ll * 8 + ct) * 4 + kc) * 64 + lane) * 8 + j;
  wph[dst] = h;
  wpl[dst] = l;
}

// ---------------- bucketed CSR, XCD-partitioned ----------------
__global__ __launch_bounds__(256) void k_bucket(const int* __restrict__ s1,
                                                const int* __restrict__ d1,
                                                const int* __restrict__ s2,
                                                const int* __restrict__ d2,
                                                int* __restrict__ cur,
                                                int* __restrict__ ssrc,
                                                int netot, int nt) {
  const int part = blockIdx.x & 7;
  const int chunk = blockIdx.x >> 3;
  const int nchunk = gridDim.x >> 3;
  const int psz = nt >> 3;
  const int lo = part * psz;
  const int hi = (part == 7) ? nt : lo + psz;
  for (int e = chunk * 256 + threadIdx.x; e < netot; e += nchunk * 256) {
    int s, d;
    if (e < NE) { s = s1[e]; d = d1[e]; }
    else        { s = s2[e - NE] + NN; d = d2[e - NE] + NN; }
    if (d >= lo && d < hi) {
      int r = atomicAdd(&cur[d], 1);
      if (r < CAP) ssrc[((size_t)d << 6) + r] = s;
    }
  }
}

// ---------------- linear via split-bf16 MFMA ----------------
__global__ __launch_bounds__(256) void k_linear(const ushort* __restrict__ Ahi,
                                                const ushort* __restrict__ Alo,
                                                const int* __restrict__ iA,
                                                const int* __restrict__ iB,
                                                const ushort* __restrict__ wph,
                                                const ushort* __restrict__ wpl,
                                                const float* __restrict__ a_src,
                                                const float* __restrict__ a_dst,
                                                ushort* __restrict__ hlinb,
                                                float* __restrict__ asrc,
                                                float* __restrict__ adst, int ntot) {
  const int lane = threadIdx.x & 63;
  const int wv = threadIdx.x >> 6;
  const int m0 = blockIdx.x * 64 + wv * 16;
  const int ln = lane & 15, lh = lane >> 4;

  int m = m0 + ln;
  int mc = min(m, ntot - 1);
  int gr = mc;
  if (iA) gr = (mc < NN) ? iA[mc] : iB[mc - NN];
  const size_t abase = (size_t)gr * 128 + lh * 8;

  bf16x8 ah[4], al[4];
#pragma unroll
  for (int kc = 0; kc < 4; kc++) {
    ah[kc] = *(const bf16x8*)(Ahi + abase + kc * 32);
    al[kc] = *(const bf16x8*)(Alo + abase + kc * 32);
  }

  f32x4 acc[8];
#pragma unroll
  for (int ct = 0; ct < 8; ct++) acc[ct] = (f32x4){0.f, 0.f, 0.f, 0.f};

#pragma unroll
  for (int ct = 0; ct < 8; ct++) {
    const ushort* bh = wph + (size_t)ct * 2048 + lane * 8;
    const ushort* bl = wpl + (size_t)ct * 2048 + lane * 8;
#pragma unroll
    for (int kc = 0; kc < 4; kc++) {
      bf16x8 vh = *(const bf16x8*)(bh + kc * 512);
      bf16x8 vl = *(const bf16x8*)(bl + kc * 512);
      acc[ct] = __builtin_amdgcn_mfma_f32_16x16x32_bf16(ah[kc], vh, acc[ct], 0, 0, 0);
      acc[ct] = __builtin_amdgcn_mfma_f32_16x16x32_bf16(al[kc], vh, acc[ct], 0, 0, 0);
      acc[ct] = __builtin_amdgcn_mfma_f32_16x16x32_bf16(ah[kc], vl, acc[ct], 0, 0, 0);
    }
  }

  const int rbase = m0 + lh * 4;
#pragma unroll
  for (int r = 0; r < 4; r++) {
    int row = rbase + r;
    if (row < ntot) {
      ushort* dst = hlinb + (size_t)row * 128 + ln;
#pragma unroll
      for (int ct = 0; ct < 8; ct++) dst[ct * 16] = f2bf(acc[ct][r]);
    }
  }

  float av[8], dv[8];
#pragma unroll
  for (int ct = 0; ct < 8; ct++) {
    av[ct] = a_src[ct * 16 + ln];
    dv[ct] = a_dst[ct * 16 + ln];
  }
#pragma unroll
  for (int r = 0; r < 4; r++) {
    float s0 = 0.f, s1 = 0.f, s2 = 0.f, s3 = 0.f;
    float d0 = 0.f, d1 = 0.f, d2 = 0.f, d3 = 0.f;
#pragma unroll
    for (int ct = 0; ct < 8; ct++) {
      float x = acc[ct][r];
      if ((ct >> 1) == 0) { s0 += x * av[ct]; d0 += x * dv[ct]; }
      else if ((ct >> 1) == 1) { s1 += x * av[ct]; d1 += x * dv[ct]; }
      else if ((ct >> 1) == 2) { s2 += x * av[ct]; d2 += x * dv[ct]; }
      else { s3 += x * av[ct]; d3 += x * dv[ct]; }
    }
#pragma unroll
    for (int off = 1; off < 16; off <<= 1) {
      s0 += __shfl_xor(s0, off); s1 += __shfl_xor(s1, off);
      s2 += __shfl_xor(s2, off); s3 += __shfl_xor(s3, off);
      d0 += __shfl_xor(d0, off); d1 += __shfl_xor(d1, off);
      d2 += __shfl_xor(d2, off); d3 += __shfl_xor(d3, off);
    }
    int row = rbase + r;
    if (ln == 0 && row < ntot) {
      ((float4*)asrc)[row] = make_float4(s0, s1, s2, s3);
      ((float4*)adst)[row] = make_float4(d0, d1, d2, d3);
    }
  }
}

// ---------------- aggregate (r8 structure, bf16 rows, bucketed edges) -------
__global__ __launch_bounds__(256) void k_aggregate(const ushort* __restrict__ hlinb,
                                                   const float* __restrict__ asrcv,
                                                   const float* __restrict__ adstv,
                                                   const int* __restrict__ cnt,
                                                   const int* __restrict__ ssrc,
                                                   const float* __restrict__ bias,
                                                   ushort* __restrict__ h_hi,
                                                   ushort* __restrict__ h_lo, int ntot) {
  const int lane = threadIdx.x & 63;
  const int n = blockIdx.x * 4 + (threadIdx.x >> 6);
  if (n >= ntot) return;
  const int p = lane >> 5;
  const int c = lane & 31;
  const int hc = c >> 3;
  const int sub = lane & 15;
  const int hs = lane >> 4;
  const size_t beg = (size_t)n << 6;
  const int deg = min(cnt[n], CAP);

  const float adh_hs = adstv[n * 4 + hs];
  const float pselfc = __expf(leaky(asrcv[n * 4 + hc] + adstv[n * 4 + hc]));

  ushort4 hb = ((const ushort4*)hlinb)[(size_t)n * 32 + c];
  float4 hv = make_float4(bf2f(hb.x), bf2f(hb.y), bf2f(hb.z), bf2f(hb.w));
  float4 acc;
  float dh;
  if (p == 0) {
    acc = make_float4(pselfc * hv.x, pselfc * hv.y, pselfc * hv.z, pselfc * hv.w);
    dh = pselfc;
  } else {
    acc = make_float4(0.f, 0.f, 0.f, 0.f);
    dh = 0.f;
  }

  for (int base = 0; base < deg; base += 16) {
    int cnt16 = deg - base; if (cnt16 > 16) cnt16 = 16;
    int s = n;
    float px = 0.f;
    if (sub < cnt16) {
      s = ssrc[beg + base + sub];
      px = __expf(leaky(asrcv[s * 4 + hs] + adh_hs));
    }
    int sj[8]; float ex[8]; ushort4 ld[8];
#pragma unroll
    for (int jj = 0; jj < 8; jj++) {
      int e = 2 * jj + p;
      sj[jj] = __shfl(s, e);
      ex[jj] = __shfl(px, hc * 16 + e);
      ld[jj] = ((const ushort4*)hlinb)[(size_t)sj[jj] * 32 + c];
    }
#pragma unroll
    for (int jj = 0; jj < 8; jj++) {
      acc.x += ex[jj] * bf2f(ld[jj].x);
      acc.y += ex[jj] * bf2f(ld[jj].y);
      acc.z += ex[jj] * bf2f(ld[jj].z);
      acc.w += ex[jj] * bf2f(ld[jj].w);
      dh += ex[jj];
    }
  }

  acc.x += __shfl_xor(acc.x, 32);
  acc.y += __shfl_xor(acc.y, 32);
  acc.z += __shfl_xor(acc.z, 32);
  acc.w += __shfl_xor(acc.w, 32);
  dh += __shfl_xor(dh, 32);

  float inv = 1.f / (dh + GEPS);
  float4 bv = ((const float4*)bias)[c];
  if (p == 0) {
    float4 o;
    o.x = fmaxf(acc.x * inv + bv.x, 0.f);
    o.y = fmaxf(acc.y * inv + bv.y, 0.f);
    o.z = fmaxf(acc.z * inv + bv.z, 0.f);
    o.w = fmaxf(acc.w * inv + bv.w, 0.f);
    ushort4 uh, ul;
    uh.x = f2bf(o.x); ul.x = f2bf(o.x - bf2f(uh.x));
    uh.y = f2bf(o.y); ul.y = f2bf(o.y - bf2f(uh.y));
    uh.z = f2bf(o.z); ul.z = f2bf(o.z - bf2f(uh.z));
    uh.w = f2bf(o.w); ul.w = f2bf(o.w - bf2f(uh.w));
    ((ushort4*)h_hi)[(size_t)n * 32 + c] = uh;
    ((ushort4*)h_lo)[(size_t)n * 32 + c] = ul;
  }
}

// ---------------- pool phase 1: per-node gate e = exp(sigmoid(h.gw + gb)) ---
// 4 nodes per wave (2 per 32-lane half); lane c covers 4 dims; 5-shfl reduce.
__global__ __launch_bounds__(256) void k_gate(const ushort* __restrict__ hh,
                                              const ushort* __restrict__ hl,
                                              const float* __restrict__ gate_w,
                                              const float* __restrict__ gate_b,
                                              float* __restrict__ ev) {
  const int lane = threadIdx.x & 63;
  const int wv = threadIdx.x >> 6;
  const int p = lane >> 5, c = lane & 31;
  const int base = (blockIdx.x * 4 + wv) * 4;
  const float gb = gate_b[0];
  const float4 gv = ((const float4*)gate_w)[c];
#pragma unroll
  for (int i = 0; i < 2; i++) {
    int n = base + i * 2 + p;
    if (n < NN) {
      ushort4 h4 = ((const ushort4*)hh)[(size_t)n * 32 + c];
      ushort4 l4 = ((const ushort4*)hl)[(size_t)n * 32 + c];
      float d = (bf2f(h4.x) + bf2f(l4.x)) * gv.x + (bf2f(h4.y) + bf2f(l4.y)) * gv.y +
                (bf2f(h4.z) + bf2f(l4.z)) * gv.z + (bf2f(h4.w) + bf2f(l4.w)) * gv.w;
#pragma unroll
      for (int off = 1; off < 32; off <<= 1) d += __shfl_xor(d, off);
      float sg = 1.f / (1.f + __expf(-(d + gb)));
      if (c == 0) ev[n] = __expf(sg);
    }
  }
}

// ---------------- pool phase 2: weighted sum (dim-parallel streaming) -------
__global__ __launch_bounds__(256) void k_wsum(const ushort* __restrict__ hh,
                                              const ushort* __restrict__ hl,
                                              const float* __restrict__ ev,
                                              float* __restrict__ acc_out) {
  __shared__ float sred[129];
  const int t = threadIdx.x;
  const int lane = t & 63;
  const int widg = blockIdx.x * 4 + (t >> 6);
  const int nw = gridDim.x * 4;
  float acc0 = 0.f, acc1 = 0.f, se = 0.f;
  for (int n = widg; n < NN; n += nw) {
    ushort2 h2 = ((const ushort2*)hh)[(size_t)n * 64 + lane];
    ushort2 l2 = ((const ushort2*)hl)[(size_t)n * 64 + lane];
    float e = ev[n];
    acc0 += e * (bf2f(h2.x) + bf2f(l2.x));
    acc1 += e * (bf2f(h2.y) + bf2f(l2.y));
    if (lane == 0) se += e;
  }
  if (t < 129) sred[t] = 0.f;
  __syncthreads();
  atomicAdd(&sred[lane * 2], acc0);
  atomicAdd(&sred[lane * 2 + 1], acc1);
  if (lane == 0) atomicAdd(&sred[128], se);
  __syncthreads();
  if (t < 129) atomicAdd(&acc_out[t], sred[t]);
}

// ---------------- final MLP ----------------
__global__ __launch_bounds__(128) void k_mlp(const float* __restrict__ p1,
                                             const float* __restrict__ p2,
                                             const float* __restrict__ fc1_w,
                                             const float* __restrict__ fc1_b,
                                             const float* __restrict__ fc2_w,
                                             const float* __restrict__ fc2_b,
                                             float* __restrict__ out) {
  __shared__ float cat[256];
  __shared__ float red[2];
  const int t = threadIdx.x;
  cat[t] = p1[t] / p1[128];
  cat[128 + t] = p2[t] / p2[128];
  __syncthreads();
  float a = fc1_b[t];
  for (int k = 0; k < 256; k++) a += cat[k] * fc1_w[k * 128 + t];
  a = fmaxf(a, 0.f);
  float v = a * fc2_w[t];
#pragma unroll
  for (int off = 1; off < 64; off <<= 1) v += __shfl_xor(v, off);
  if ((t & 63) == 0) red[t >> 6] = v;
  __syncthreads();
  if (t == 0) out[0] = red[0] + red[1] + fc2_b[0];
}

extern "C" void kernel_launch(void* const* d_in, const int* in_sizes, int n_in,
                              void* d_out, int out_size, void* d_ws, size_t ws_size,
                              hipStream_t stream) {
  (void)in_sizes; (void)n_in; (void)out_size;
  const int* x1 = (const int*)d_in[0];
  const int* x2 = (const int*)d_in[1];
  const int* ei1 = (const int*)d_in[2];
  const int* ei2 = (const int*)d_in[3];
  const float* embed = (const float*)d_in[4];
  const float* W = (const float*)d_in[5];
  const float* attS = (const float*)d_in[6];
  const float* attD = (const float*)d_in[7];
  const float* bias = (const float*)d_in[8];
  const float* gw = (const float*)d_in[9];
  const float* gb = (const float*)d_in[10];
  const float* f1w = (const float*)d_in[11];
  const float* f1b = (const float*)d_in[12];
  const float* f2w = (const float*)d_in[13];
  const float* f2b = (const float*)d_in[14];
  float* out = (float*)d_out;

  auto req = [](int nt) {
    size_t s = 0;
    auto pad = [&](size_t b) { s = (s + b + 255) & ~size_t(255); };
    pad(size_t(nt) * DIM * 2);        // h_hi
    pad(size_t(nt) * DIM * 2);        // h_lo
    pad(size_t(nt) * DIM * 2);        // hlinb (bf16)
    pad(size_t(VOCAB) * DIM * 2);     // e_hi
    pad(size_t(VOCAB) * DIM * 2);     // e_lo
    pad(3 * 16384 * 2);               // wp_hi
    pad(3 * 16384 * 2);               // wp_lo
    pad(size_t(nt) * 16);             // asrc
    pad(size_t(nt) * 16);             // adst
    pad(size_t(nt) * 4);              // cur
    pad(size_t(nt) * CAP * 4);        // ssrc buckets
    pad(size_t(NN) * 4);              // ev
    pad(2 * 129 * 4);                 // pool
    return s;
  };
  const bool combined = ws_size >= req(2 * NN);
  const int nt = combined ? 2 * NN : NN;
  const int net = combined ? 2 * NE : NE;

  char* ws = (char*)d_ws;
  size_t off = 0;
  auto alloc = [&](size_t bytes) {
    void* p = ws + off;
    off = (off + bytes + 255) & ~size_t(255);
    return p;
  };
  ushort* h_hi = (ushort*)alloc(size_t(nt) * DIM * 2);
  ushort* h_lo = (ushort*)alloc(size_t(nt) * DIM * 2);
  ushort* hlinb = (ushort*)alloc(size_t(nt) * DIM * 2);
  ushort* e_hi = (ushort*)alloc(size_t(VOCAB) * DIM * 2);
  ushort* e_lo = (ushort*)alloc(size_t(VOCAB) * DIM * 2);
  ushort* wp_hi = (ushort*)alloc(3 * 16384 * 2);
  ushort* wp_lo = (ushort*)alloc(3 * 16384 * 2);
  float* asrc = (float*)alloc(size_t(nt) * 16);
  float* adst = (float*)alloc(size_t(nt) * 16);
  int* cur = (int*)alloc(size_t(nt) * 4);
  int* ssrc = (int*)alloc(size_t(nt) * CAP * 4);
  float* ev = (float*)alloc(size_t(NN) * 4);
  float* pool = (float*)alloc(2 * 129 * 4);

  hipMemsetAsync(pool, 0, 2 * 129 * 4, stream);

  const int esplit4 = VOCAB * DIM / 4;
  k_split<<<(esplit4 + 255) / 256, 256, 0, stream>>>(embed, e_hi, e_lo, esplit4);
  k_packw<<<(3 * 128 * 128 + 255) / 256, 256, 0, stream>>>(W, wp_hi, wp_lo);

  const int lgrid = (nt + 63) / 64;
  const int nchunk = (net + 256 * 8 - 1) / (256 * 8);
  const int ggrid = (NN + 15) / 16;

  auto run_graphs = [&](const int* xA, const int* xB, const int* eA, const int* eB) {
    hipMemsetAsync(cur, 0, size_t(nt) * 4, stream);
    k_bucket<<<nchunk * 8, 256, 0, stream>>>(eA, eA + NE, eB, eB + NE, cur, ssrc, net, nt);
    for (int l = 0; l < 3; ++l) {
      if (l == 0) {
        k_linear<<<lgrid, 256, 0, stream>>>(
            e_hi, e_lo, xA, xB, wp_hi, wp_lo, attS, attD, hlinb, asrc, adst, nt);
      } else {
        k_linear<<<lgrid, 256, 0, stream>>>(
            h_hi, h_lo, nullptr, nullptr, wp_hi + l * 16384, wp_lo + l * 16384,
            attS + l * DIM, attD + l * DIM, hlinb, asrc, adst, nt);
      }
      k_aggregate<<<(nt + 3) / 4, 256, 0, stream>>>(
          hlinb, asrc, adst, cur, ssrc, bias + l * DIM, h_hi, h_lo, nt);
    }
  };

  auto do_pool = [&](const ushort* hh, const ushort* hl, float* slot) {
    k_gate<<<ggrid, 256, 0, stream>>>(hh, hl, gw, gb, ev);
    k_wsum<<<512, 256, 0, stream>>>(hh, hl, ev, slot);
  };

  if (combined) {
    run_graphs(x1, x2, ei1, ei2);
    do_pool(h_hi, h_lo, pool);
    do_pool(h_hi + size_t(NN) * DIM, h_lo + size_t(NN) * DIM, pool + 129);
  } else {
    run_graphs(x1, x1, ei1, ei1);
    do_pool(h_hi, h_lo, pool);
    run_graphs(x2, x2, ei2, ei2);
    do_pool(h_hi, h_lo, pool + 129);
  }
  k_mlp<<<1, 128, 0, stream>>>(pool, pool + 129, f1w, f1b, f2w, f2b, out);
}

// Round 16
// 420.456 us; speedup vs baseline: 1.7738x; 1.0096x over previous
//
#include <hip/hip_runtime.h>
#include <hip/hip_bf16.h>

#define NN 50000
#define NE 600000
#define DIM 128
#define VOCAB 30000
#define NEG 0.2f
#define GEPS 1e-16f
#define CAP 64

typedef __attribute__((ext_vector_type(8))) short bf16x8;
typedef __attribute__((ext_vector_type(4))) float f32x4;

__device__ __forceinline__ float leaky(float x) { return x > 0.f ? x : NEG * x; }

// bf16 split helpers (RNE)
__device__ __forceinline__ ushort f2bf(float f) {
  uint x = __float_as_uint(f);
  x += 0x7FFFu + ((x >> 16) & 1u);
  return (ushort)(x >> 16);
}
__device__ __forceinline__ float bf2f(ushort u) { return __uint_as_float(((uint)u) << 16); }
__device__ __forceinline__ float bflo(uint u) { return __uint_as_float(u << 16); }
__device__ __forceinline__ float bfhi(uint u) { return __uint_as_float(u & 0xFFFF0000u); }

// ---------------- one-time: split embed into bf16 hi/lo ----------------
__global__ __launch_bounds__(256) void k_split(const float* __restrict__ src,
                                               ushort* __restrict__ hi,
                                               ushort* __restrict__ lo, int n4) {
  int i = blockIdx.x * 256 + threadIdx.x;
  if (i >= n4) return;
  float4 v = ((const float4*)src)[i];
  ushort4 h, l;
  h.x = f2bf(v.x); l.x = f2bf(v.x - bf2f(h.x));
  h.y = f2bf(v.y); l.y = f2bf(v.y - bf2f(h.y));
  h.z = f2bf(v.z); l.z = f2bf(v.z - bf2f(h.z));
  h.w = f2bf(v.w); l.w = f2bf(v.w - bf2f(h.w));
  ((ushort4*)hi)[i] = h;
  ((ushort4*)lo)[i] = l;
}

// ---------------- one-time: split W + pack into MFMA B-fragment order ------
__global__ __launch_bounds__(256) void k_packw(const float* __restrict__ W,
                                               ushort* __restrict__ wph,
                                               ushort* __restrict__ wpl) {
  int i = blockIdx.x * 256 + threadIdx.x;
  if (i >= 3 * 128 * 128) return;
  int ll = i >> 14, rem = i & 16383, k = rem >> 7, n = rem & 127;
  float v = W[i];
  ushort h = f2bf(v), l = f2bf(v - bf2f(h));
  int ct = n >> 4, ln = n & 15, kc = k >> 5, kr = k & 31;
  int lane = (kr >> 3) * 16 + ln, j = kr & 7;
  size_t dst = ((((size_t)ll * 8 + ct) * 4 + kc) * 64 + lane) * 8 + j;
  wph[dst] = h;
  wpl[dst] = l;
}

// ---------------- bucketed CSR, XCD-partitioned ----------------
__global__ __launch_bounds__(256) void k_bucket(const int* __restrict__ s1,
                                                const int* __restrict__ d1,
                                                const int* __restrict__ s2,
                                                const int* __restrict__ d2,
                                                int* __restrict__ cur,
                                                int* __restrict__ ssrc,
                                                int netot, int nt) {
  const int part = blockIdx.x & 7;
  const int chunk = blockIdx.x >> 3;
  const int nchunk = gridDim.x >> 3;
  const int psz = nt >> 3;
  const int lo = part * psz;
  const int hi = (part == 7) ? nt : lo + psz;
  for (int e = chunk * 256 + threadIdx.x; e < netot; e += nchunk * 256) {
    int s, d;
    if (e < NE) { s = s1[e]; d = d1[e]; }
    else        { s = s2[e - NE] + NN; d = d2[e - NE] + NN; }
    if (d >= lo && d < hi) {
      int r = atomicAdd(&cur[d], 1);
      if (r < CAP) ssrc[((size_t)d << 6) + r] = s;
    }
  }
}

// ---------------- linear via split-bf16 MFMA ----------------
__global__ __launch_bounds__(256) void k_linear(const ushort* __restrict__ Ahi,
                                                const ushort* __restrict__ Alo,
                                                const int* __restrict__ iA,
                                                const int* __restrict__ iB,
                                                const ushort* __restrict__ wph,
                                                const ushort* __restrict__ wpl,
                                                const float* __restrict__ a_src,
                                                const float* __restrict__ a_dst,
                                                ushort* __restrict__ hlinb,
                                                float* __restrict__ asrc,
                                                float* __restrict__ adst, int ntot) {
  const int lane = threadIdx.x & 63;
  const int wv = threadIdx.x >> 6;
  const int m0 = blockIdx.x * 64 + wv * 16;
  const int ln = lane & 15, lh = lane >> 4;

  int m = m0 + ln;
  int mc = min(m, ntot - 1);
  int gr = mc;
  if (iA) gr = (mc < NN) ? iA[mc] : iB[mc - NN];
  const size_t abase = (size_t)gr * 128 + lh * 8;

  bf16x8 ah[4], al[4];
#pragma unroll
  for (int kc = 0; kc < 4; kc++) {
    ah[kc] = *(const bf16x8*)(Ahi + abase + kc * 32);
    al[kc] = *(const bf16x8*)(Alo + abase + kc * 32);
  }

  f32x4 acc[8];
#pragma unroll
  for (int ct = 0; ct < 8; ct++) acc[ct] = (f32x4){0.f, 0.f, 0.f, 0.f};

#pragma unroll
  for (int ct = 0; ct < 8; ct++) {
    const ushort* bh = wph + (size_t)ct * 2048 + lane * 8;
    const ushort* bl = wpl + (size_t)ct * 2048 + lane * 8;
#pragma unroll
    for (int kc = 0; kc < 4; kc++) {
      bf16x8 vh = *(const bf16x8*)(bh + kc * 512);
      bf16x8 vl = *(const bf16x8*)(bl + kc * 512);
      acc[ct] = __builtin_amdgcn_mfma_f32_16x16x32_bf16(ah[kc], vh, acc[ct], 0, 0, 0);
      acc[ct] = __builtin_amdgcn_mfma_f32_16x16x32_bf16(al[kc], vh, acc[ct], 0, 0, 0);
      acc[ct] = __builtin_amdgcn_mfma_f32_16x16x32_bf16(ah[kc], vl, acc[ct], 0, 0, 0);
    }
  }

  const int rbase = m0 + lh * 4;
#pragma unroll
  for (int r = 0; r < 4; r++) {
    int row = rbase + r;
    if (row < ntot) {
      ushort* dst = hlinb + (size_t)row * 128 + ln;
#pragma unroll
      for (int ct = 0; ct < 8; ct++) dst[ct * 16] = f2bf(acc[ct][r]);
    }
  }

  float av[8], dv[8];
#pragma unroll
  for (int ct = 0; ct < 8; ct++) {
    av[ct] = a_src[ct * 16 + ln];
    dv[ct] = a_dst[ct * 16 + ln];
  }
#pragma unroll
  for (int r = 0; r < 4; r++) {
    float s0 = 0.f, s1 = 0.f, s2 = 0.f, s3 = 0.f;
    float d0 = 0.f, d1 = 0.f, d2 = 0.f, d3 = 0.f;
#pragma unroll
    for (int ct = 0; ct < 8; ct++) {
      float x = acc[ct][r];
      if ((ct >> 1) == 0) { s0 += x * av[ct]; d0 += x * dv[ct]; }
      else if ((ct >> 1) == 1) { s1 += x * av[ct]; d1 += x * dv[ct]; }
      else if ((ct >> 1) == 2) { s2 += x * av[ct]; d2 += x * dv[ct]; }
      else { s3 += x * av[ct]; d3 += x * dv[ct]; }
    }
#pragma unroll
    for (int off = 1; off < 16; off <<= 1) {
      s0 += __shfl_xor(s0, off); s1 += __shfl_xor(s1, off);
      s2 += __shfl_xor(s2, off); s3 += __shfl_xor(s3, off);
      d0 += __shfl_xor(d0, off); d1 += __shfl_xor(d1, off);
      d2 += __shfl_xor(d2, off); d3 += __shfl_xor(d3, off);
    }
    int row = rbase + r;
    if (ln == 0 && row < ntot) {
      ((float4*)asrc)[row] = make_float4(s0, s1, s2, s3);
      ((float4*)adst)[row] = make_float4(d0, d1, d2, d3);
    }
  }
}

// ---------------- aggregate v6: quad-split, 16B lanes ----------------
// lane = (group q=lane>>4 handling edge slots e%4==q, dim-block c=lane&15
// covering dims c*8..c*8+7). Each lane loads ushort8 (16B); 16 lanes = one
// row, wave load = 4 rows. Per 16-edge chunk: 4 steps (2 shfl + 1 dwordx4 +
// 17 VALU each), all loads issued before consumption. 2-level cross-group
// reduce (xor 16, 32). Staging (16 slots x 4 heads) unchanged from v3.
__global__ __launch_bounds__(256) void k_aggregate(const ushort* __restrict__ hlinb,
                                                   const float* __restrict__ asrcv,
                                                   const float* __restrict__ adstv,
                                                   const int* __restrict__ cnt,
                                                   const int* __restrict__ ssrc,
                                                   const float* __restrict__ bias,
                                                   ushort* __restrict__ h_hi,
                                                   ushort* __restrict__ h_lo, int ntot) {
  const int lane = threadIdx.x & 63;
  const int n = blockIdx.x * 4 + (threadIdx.x >> 6);
  if (n >= ntot) return;
  const int q = lane >> 4;        // edge group (also staging head hs)
  const int c = lane & 15;        // dim block (dims c*8..c*8+7), also staging sub
  const int hc2 = c >> 2;         // head of this lane's dims
  const size_t beg = (size_t)n << 6;
  const int deg = min(cnt[n], CAP);

  const float adh_hs = adstv[n * 4 + q];
  const float pselfc = __expf(leaky(asrcv[n * 4 + hc2] + adstv[n * 4 + hc2]));

  const uint4* rowp = (const uint4*)(hlinb + (size_t)n * 128 + c * 8);
  uint4 hb = *rowp;
  float acc[8];
  float dh;
  if (q == 0) {
    acc[0] = pselfc * bflo(hb.x); acc[1] = pselfc * bfhi(hb.x);
    acc[2] = pselfc * bflo(hb.y); acc[3] = pselfc * bfhi(hb.y);
    acc[4] = pselfc * bflo(hb.z); acc[5] = pselfc * bfhi(hb.z);
    acc[6] = pselfc * bflo(hb.w); acc[7] = pselfc * bfhi(hb.w);
    dh = pselfc;
  } else {
#pragma unroll
    for (int i = 0; i < 8; i++) acc[i] = 0.f;
    dh = 0.f;
  }

  for (int base = 0; base < deg; base += 16) {
    int cnt16 = deg - base; if (cnt16 > 16) cnt16 = 16;
    int s = n;
    float px = 0.f;
    if (c < cnt16) {               // lane (q*16+c) stages slot c for head q
      s = ssrc[beg + base + c];
      px = __expf(leaky(asrcv[s * 4 + q] + adh_hs));
    }
    int sj[4]; float ex[4]; uint4 ld[4];
#pragma unroll
    for (int jj = 0; jj < 4; jj++) {
      int e = 4 * jj + q;
      sj[jj] = __shfl(s, e);                  // slot e staged on lane e (head 0 copy)
      ex[jj] = __shfl(px, hc2 * 16 + e);      // weight for this lane's head
      ld[jj] = *(const uint4*)(hlinb + (size_t)sj[jj] * 128 + c * 8);
    }
#pragma unroll
    for (int jj = 0; jj < 4; jj++) {
      float e = ex[jj];
      acc[0] += e * bflo(ld[jj].x); acc[1] += e * bfhi(ld[jj].x);
      acc[2] += e * bflo(ld[jj].y); acc[3] += e * bfhi(ld[jj].y);
      acc[4] += e * bflo(ld[jj].z); acc[5] += e * bfhi(ld[jj].z);
      acc[6] += e * bflo(ld[jj].w); acc[7] += e * bfhi(ld[jj].w);
      dh += e;
    }
  }

#pragma unroll
  for (int i = 0; i < 8; i++) {
    acc[i] += __shfl_xor(acc[i], 16);
    acc[i] += __shfl_xor(acc[i], 32);
  }
  dh += __shfl_xor(dh, 16);
  dh += __shfl_xor(dh, 32);

  if (q == 0) {
    float inv = 1.f / (dh + GEPS);
    const float4 bv0 = ((const float4*)bias)[c * 2];
    const float4 bv1 = ((const float4*)bias)[c * 2 + 1];
    float o[8];
    o[0] = fmaxf(acc[0] * inv + bv0.x, 0.f);
    o[1] = fmaxf(acc[1] * inv + bv0.y, 0.f);
    o[2] = fmaxf(acc[2] * inv + bv0.z, 0.f);
    o[3] = fmaxf(acc[3] * inv + bv0.w, 0.f);
    o[4] = fmaxf(acc[4] * inv + bv1.x, 0.f);
    o[5] = fmaxf(acc[5] * inv + bv1.y, 0.f);
    o[6] = fmaxf(acc[6] * inv + bv1.z, 0.f);
    o[7] = fmaxf(acc[7] * inv + bv1.w, 0.f);
    ushort uh[8], ul[8];
#pragma unroll
    for (int i = 0; i < 8; i++) {
      uh[i] = f2bf(o[i]);
      ul[i] = f2bf(o[i] - bf2f(uh[i]));
    }
    uint4 ph, pl;
    ph.x = (uint)uh[0] | ((uint)uh[1] << 16);
    ph.y = (uint)uh[2] | ((uint)uh[3] << 16);
    ph.z = (uint)uh[4] | ((uint)uh[5] << 16);
    ph.w = (uint)uh[6] | ((uint)uh[7] << 16);
    pl.x = (uint)ul[0] | ((uint)ul[1] << 16);
    pl.y = (uint)ul[2] | ((uint)ul[3] << 16);
    pl.z = (uint)ul[4] | ((uint)ul[5] << 16);
    pl.w = (uint)ul[6] | ((uint)ul[7] << 16);
    *(uint4*)(h_hi + (size_t)n * 128 + c * 8) = ph;
    *(uint4*)(h_lo + (size_t)n * 128 + c * 8) = pl;
  }
}

// ---------------- pool phase 1: per-node gate e = exp(sigmoid(h.gw + gb)) ---
__global__ __launch_bounds__(256) void k_gate(const ushort* __restrict__ hh,
                                              const ushort* __restrict__ hl,
                                              const float* __restrict__ gate_w,
                                              const float* __restrict__ gate_b,
                                              float* __restrict__ ev) {
  const int lane = threadIdx.x & 63;
  const int wv = threadIdx.x >> 6;
  const int p = lane >> 5, c = lane & 31;
  const int base = (blockIdx.x * 4 + wv) * 4;
  const float gb = gate_b[0];
  const float4 gv = ((const float4*)gate_w)[c];
#pragma unroll
  for (int i = 0; i < 2; i++) {
    int n = base + i * 2 + p;
    if (n < NN) {
      ushort4 h4 = ((const ushort4*)hh)[(size_t)n * 32 + c];
      ushort4 l4 = ((const ushort4*)hl)[(size_t)n * 32 + c];
      float d = (bf2f(h4.x) + bf2f(l4.x)) * gv.x + (bf2f(h4.y) + bf2f(l4.y)) * gv.y +
                (bf2f(h4.z) + bf2f(l4.z)) * gv.z + (bf2f(h4.w) + bf2f(l4.w)) * gv.w;
#pragma unroll
      for (int off = 1; off < 32; off <<= 1) d += __shfl_xor(d, off);
      float sg = 1.f / (1.f + __expf(-(d + gb)));
      if (c == 0) ev[n] = __expf(sg);
    }
  }
}

// ---------------- pool phase 2: weighted sum (dim-parallel streaming) -------
__global__ __launch_bounds__(256) void k_wsum(const ushort* __restrict__ hh,
                                              const ushort* __restrict__ hl,
                                              const float* __restrict__ ev,
                                              float* __restrict__ acc_out) {
  __shared__ float sred[129];
  const int t = threadIdx.x;
  const int lane = t & 63;
  const int widg = blockIdx.x * 4 + (t >> 6);
  const int nw = gridDim.x * 4;
  float acc0 = 0.f, acc1 = 0.f, se = 0.f;
  for (int n = widg; n < NN; n += nw) {
    ushort2 h2 = ((const ushort2*)hh)[(size_t)n * 64 + lane];
    ushort2 l2 = ((const ushort2*)hl)[(size_t)n * 64 + lane];
    float e = ev[n];
    acc0 += e * (bf2f(h2.x) + bf2f(l2.x));
    acc1 += e * (bf2f(h2.y) + bf2f(l2.y));
    if (lane == 0) se += e;
  }
  if (t < 129) sred[t] = 0.f;
  __syncthreads();
  atomicAdd(&sred[lane * 2], acc0);
  atomicAdd(&sred[lane * 2 + 1], acc1);
  if (lane == 0) atomicAdd(&sred[128], se);
  __syncthreads();
  if (t < 129) atomicAdd(&acc_out[t], sred[t]);
}

// ---------------- final MLP ----------------
__global__ __launch_bounds__(128) void k_mlp(const float* __restrict__ p1,
                                             const float* __restrict__ p2,
                                             const float* __restrict__ fc1_w,
                                             const float* __restrict__ fc1_b,
                                             const float* __restrict__ fc2_w,
                                             const float* __restrict__ fc2_b,
                                             float* __restrict__ out) {
  __shared__ float cat[256];
  __shared__ float red[2];
  const int t = threadIdx.x;
  cat[t] = p1[t] / p1[128];
  cat[128 + t] = p2[t] / p2[128];
  __syncthreads();
  float a = fc1_b[t];
  for (int k = 0; k < 256; k++) a += cat[k] * fc1_w[k * 128 + t];
  a = fmaxf(a, 0.f);
  float v = a * fc2_w[t];
#pragma unroll
  for (int off = 1; off < 64; off <<= 1) v += __shfl_xor(v, off);
  if ((t & 63) == 0) red[t >> 6] = v;
  __syncthreads();
  if (t == 0) out[0] = red[0] + red[1] + fc2_b[0];
}

extern "C" void kernel_launch(void* const* d_in, const int* in_sizes, int n_in,
                              void* d_out, int out_size, void* d_ws, size_t ws_size,
                              hipStream_t stream) {
  (void)in_sizes; (void)n_in; (void)out_size;
  const int* x1 = (const int*)d_in[0];
  const int* x2 = (const int*)d_in[1];
  const int* ei1 = (const int*)d_in[2];
  const int* ei2 = (const int*)d_in[3];
  const float* embed = (const float*)d_in[4];
  const float* W = (const float*)d_in[5];
  const float* attS = (const float*)d_in[6];
  const float* attD = (const float*)d_in[7];
  const float* bias = (const float*)d_in[8];
  const float* gw = (const float*)d_in[9];
  const float* gb = (const float*)d_in[10];
  const float* f1w = (const float*)d_in[11];
  const float* f1b = (const float*)d_in[12];
  const float* f2w = (const float*)d_in[13];
  const float* f2b = (const float*)d_in[14];
  float* out = (float*)d_out;

  auto req = [](int nt) {
    size_t s = 0;
    auto pad = [&](size_t b) { s = (s + b + 255) & ~size_t(255); };
    pad(size_t(nt) * DIM * 2);        // h_hi
    pad(size_t(nt) * DIM * 2);        // h_lo
    pad(size_t(nt) * DIM * 2);        // hlinb (bf16)
    pad(size_t(VOCAB) * DIM * 2);     // e_hi
    pad(size_t(VOCAB) * DIM * 2);     // e_lo
    pad(3 * 16384 * 2);               // wp_hi
    pad(3 * 16384 * 2);               // wp_lo
    pad(size_t(nt) * 16);             // asrc
    pad(size_t(nt) * 16);             // adst
    pad(size_t(nt) * 4);              // cur
    pad(size_t(nt) * CAP * 4);        // ssrc buckets
    pad(size_t(NN) * 4);              // ev
    pad(2 * 129 * 4);                 // pool
    return s;
  };
  const bool combined = ws_size >= req(2 * NN);
  const int nt = combined ? 2 * NN : NN;
  const int net = combined ? 2 * NE : NE;

  char* ws = (char*)d_ws;
  size_t off = 0;
  auto alloc = [&](size_t bytes) {
    void* p = ws + off;
    off = (off + bytes + 255) & ~size_t(255);
    return p;
  };
  ushort* h_hi = (ushort*)alloc(size_t(nt) * DIM * 2);
  ushort* h_lo = (ushort*)alloc(size_t(nt) * DIM * 2);
  ushort* hlinb = (ushort*)alloc(size_t(nt) * DIM * 2);
  ushort* e_hi = (ushort*)alloc(size_t(VOCAB) * DIM * 2);
  ushort* e_lo = (ushort*)alloc(size_t(VOCAB) * DIM * 2);
  ushort* wp_hi = (ushort*)alloc(3 * 16384 * 2);
  ushort* wp_lo = (ushort*)alloc(3 * 16384 * 2);
  float* asrc = (float*)alloc(size_t(nt) * 16);
  float* adst = (float*)alloc(size_t(nt) * 16);
  int* cur = (int*)alloc(size_t(nt) * 4);
  int* ssrc = (int*)alloc(size_t(nt) * CAP * 4);
  float* ev = (float*)alloc(size_t(NN) * 4);
  float* pool = (float*)alloc(2 * 129 * 4);

  hipMemsetAsync(pool, 0, 2 * 129 * 4, stream);

  const int esplit4 = VOCAB * DIM / 4;
  k_split<<<(esplit4 + 255) / 256, 256, 0, stream>>>(embed, e_hi, e_lo, esplit4);
  k_packw<<<(3 * 128 * 128 + 255) / 256, 256, 0, stream>>>(W, wp_hi, wp_lo);

  const int lgrid = (nt + 63) / 64;
  const int nchunk = (net + 256 * 8 - 1) / (256 * 8);
  const int ggrid = (NN + 15) / 16;

  auto run_graphs = [&](const int* xA, const int* xB, const int* eA, const int* eB) {
    hipMemsetAsync(cur, 0, size_t(nt) * 4, stream);
    k_bucket<<<nchunk * 8, 256, 0, stream>>>(eA, eA + NE, eB, eB + NE, cur, ssrc, net, nt);
    for (int l = 0; l < 3; ++l) {
      if (l == 0) {
        k_linear<<<lgrid, 256, 0, stream>>>(
            e_hi, e_lo, xA, xB, wp_hi, wp_lo, attS, attD, hlinb, asrc, adst, nt);
      } else {
        k_linear<<<lgrid, 256, 0, stream>>>(
            h_hi, h_lo, nullptr, nullptr, wp_hi + l * 16384, wp_lo + l * 16384,
            attS + l * DIM, attD + l * DIM, hlinb, asrc, adst, nt);
      }
      k_aggregate<<<(nt + 3) / 4, 256, 0, stream>>>(
          hlinb, asrc, adst, cur, ssrc, bias + l * DIM, h_hi, h_lo, nt);
    }
  };

  auto do_pool = [&](const ushort* hh, const ushort* hl, float* slot) {
    k_gate<<<ggrid, 256, 0, stream>>>(hh, hl, gw, gb, ev);
    k_wsum<<<512, 256, 0, stream>>>(hh, hl, ev, slot);
  };

  if (combined) {
    run_graphs(x1, x2, ei1, ei2);
    do_pool(h_hi, h_lo, pool);
    do_pool(h_hi + size_t(NN) * DIM, h_lo + size_t(NN) * DIM, pool + 129);
  } else {
    run_graphs(x1, x1, ei1, ei1);
    do_pool(h_hi, h_lo, pool);
    run_graphs(x2, x2, ei2, ei2);
    do_pool(h_hi, h_lo, pool + 129);
  }
  k_mlp<<<1, 128, 0, stream>>>(pool, pool + 129, f1w, f1b, f2w, f2b, out);
}